// Round 10
// baseline (395.414 us; speedup 1.0000x reference)
//
#include <hip/hip_runtime.h>

#define NUM_USER 60000
#define NUM_ITEM 40000
#define NN 100000
#define NE 500000
#define DIM 64
#define KF 4
#define SCAN_CHUNK 512
#define NBLK_SCAN ((NN + 1 + SCAN_CHUNK - 1) / SCAN_CHUNK)
// padded slot-count upper bounds (each node rounds up to multiple of 4)
#define NEPU_MAX (NE + 3 * NUM_USER)   // 680000 user-side slots max
#define NEPI_MAX (NE + 3 * NUM_ITEM)   // 620000 item-side slots max
#define MAXU_SLOTS 44                  // register-cached user path handles <=44 slots
#define NB_U4 (NUM_USER * DIM / 4 / 256)   // 3750 user-init blocks (float4/thread)
#define NB_I (NUM_ITEM / 16)               // 2500 item-init blocks (16 nodes/block)
#define NB_SETUP (NB_U4 + NB_I)            // 6250
#define EPB (NE / NB_SETUP)                // 80 edges counted per setup block
#define NB_W0 ((NEPU_MAX + 255) / 256)
#define NB_PADI ((NUM_ITEM + 255) / 256)

// sum within each 16-lane group (butterfly: all lanes get result)
__device__ __forceinline__ float red16(float v) {
    v += __shfl_xor(v, 1);
    v += __shfl_xor(v, 2);
    v += __shfl_xor(v, 4);
    v += __shfl_xor(v, 8);
    return v;
}

__device__ __forceinline__ float b2f(unsigned short u) {
    return __uint_as_float(((unsigned)u) << 16);
}
__device__ __forceinline__ unsigned short f2b(float x) {
    unsigned u = __float_as_uint(x);
    u = (u + 0x7fffu + ((u >> 16) & 1u)) >> 16;   // RNE
    return (unsigned short)u;
}
// combined item word: high16 = T (bf16 bits), low16 = ego (bf16 bits)
__device__ __forceinline__ float cvt_lo(unsigned c) { return __uint_as_float(c << 16); }
__device__ __forceinline__ float cvt_hi(unsigned c) { return __uint_as_float(c & 0xffff0000u); }
// pack hi16 halves of two combined words: lo16(out)=hi16(c0), hi16(out)=hi16(c1)
__device__ __forceinline__ unsigned packhi(unsigned c0, unsigned c1) {
#if defined(__has_builtin) && __has_builtin(__builtin_amdgcn_perm)
    return __builtin_amdgcn_perm(c1, c0, 0x07060302u);
#else
    return (c0 >> 16) | (c1 & 0xffff0000u);
#endif
}
// mixed-butterfly level: lane keeps the value whose slot-bit matches its lane bit
__device__ __forceinline__ float mixv(float x, float y, bool b, int m) {
    return (b ? y : x) + __shfl_xor(b ? x : y, m);
}

__device__ __forceinline__ float4 softmax4(float4 s) {
    float m = fmaxf(fmaxf(s.x, s.y), fmaxf(s.z, s.w));
    float e0 = __expf(s.x - m), e1 = __expf(s.y - m);
    float e2 = __expf(s.z - m), e3 = __expf(s.w - m);
    float inv = 1.0f / (e0 + e1 + e2 + e3);
    return make_float4(e0 * inv, e1 * inv, e2 * inv, e3 * inv);
}

// Fused per-slot S/weight update (single weight buffer: every access to a
// user slot is by its owning lane, read-before-write in program order).
// softmax(S_old) reconstructed as w*(1/n). snew = w*rn + dot.
// last: S4f <- snew (final output); else w' = n*softmax_k(snew) -> wu
// (+ wi item-order scatter only when writeWi; jit read from urec record).
__device__ __forceinline__ void fused_upd(int jj, int k, float dot, bool wr,
        float* __restrict__ wu, float* __restrict__ S4f,
        const float2* __restrict__ norm2, const int* __restrict__ urec4,
        float* __restrict__ wiW, int last, int writeWi) {
    float w = wu[4 * jj + k];
    float2 nn = norm2[jj];
    float snew = fmaf(w, nn.y, dot);
    if (last) {
        if (wr) S4f[4 * jj + k] = snew;
        return;
    }
    float m2 = fmaxf(snew, __shfl_xor(snew, 16));
    m2 = fmaxf(m2, __shfl_xor(m2, 32));
    float e2 = __expf(snew - m2);
    float s2 = e2 + __shfl_xor(e2, 16);
    s2 += __shfl_xor(s2, 32);
    if (wr && nn.x > 0.0f) {
        float wn = nn.x * e2 * (1.0f / s2);
        wu[4 * jj + k] = wn;
        if (writeWi) wiW[4 * urec4[(jj << 2) + 1] + k] = wn;
    }
}

// init (vectorized 4 dims/thread) + DISTRIBUTED degree count (80 edges/block,
// threads 0..159 one endpoint each -- atomics hide under the streaming init).
__global__ void k_setup(const float* __restrict__ user, const float* __restrict__ item,
                        unsigned short* __restrict__ egoU, unsigned* __restrict__ cmbI,
                        float* __restrict__ allemb, const int* __restrict__ row0,
                        const int* __restrict__ col0, int* __restrict__ cnt) {
    int b = blockIdx.x, t = threadIdx.x;
    int ebase = b * EPB;
    if (t < EPB) atomicAdd(&cnt[row0[ebase + t]], 1);
    else if (t < 2 * EPB) atomicAdd(&cnt[col0[ebase + t - EPB]], 1);
    if (b < NB_U4) {
        // user: pure streaming copy, float4/thread
        int idx = (b * 256 + t) * 4;
        float4 v = *(const float4*)(user + idx);
        ushort4 e;
        e.x = f2b(v.x); e.y = f2b(v.y); e.z = f2b(v.z); e.w = f2b(v.w);
        *(ushort4*)(egoU + idx) = e;
        *(float4*)(allemb + idx) = v;
    } else {
        // item: 16 lanes/node, float4/lane; 16-dim norm = 4-lane reduce
        int bb = b - NB_U4;
        int lane = t & 63;
        int nodeI = bb * 16 + ((t >> 6) << 2) + (lane >> 4);
        int idx = nodeI * DIM + (lane & 15) * 4;
        float4 v = *(const float4*)(item + idx);
        float ss = v.x * v.x + v.y * v.y + v.z * v.z + v.w * v.w;
        ss += __shfl_xor(ss, 1);
        ss += __shfl_xor(ss, 2);
        float rinv = 1.0f / fmaxf(sqrtf(ss), 1e-12f);
        uint4 o;
        o.x = (((unsigned)f2b(tanhf(v.x * rinv))) << 16) | (unsigned)f2b(v.x);
        o.y = (((unsigned)f2b(tanhf(v.y * rinv))) << 16) | (unsigned)f2b(v.y);
        o.z = (((unsigned)f2b(tanhf(v.z * rinv))) << 16) | (unsigned)f2b(v.z);
        o.w = (((unsigned)f2b(tanhf(v.w * rinv))) << 16) | (unsigned)f2b(v.w);
        *(uint4*)(cmbI + idx) = o;
        *(float4*)(allemb + NUM_USER * DIM + idx) = v;
    }
}

// --- 3-stage exclusive scan over padded counts -> ptr[NN+1]; dinv fused ---
__global__ void k_scan1(const int* __restrict__ cnt, float* __restrict__ dinv,
                        int* __restrict__ ptr, int* __restrict__ bsum) {
    __shared__ int sm[SCAN_CHUNK];
    int tid = threadIdx.x;
    int idx = blockIdx.x * SCAN_CHUNK + tid;
    int d = (idx < NN) ? cnt[idx] : 0;
    if (idx < NN) dinv[idx] = (d > 0) ? rsqrtf((float)d) : 0.0f;
    int x = (d + 3) & ~3;
    sm[tid] = x;
    __syncthreads();
    for (int off = 1; off < SCAN_CHUNK; off <<= 1) {
        int v = (tid >= off) ? sm[tid - off] : 0;
        __syncthreads();
        sm[tid] += v;
        __syncthreads();
    }
    if (idx <= NN) ptr[idx] = sm[tid] - x;
    if (tid == SCAN_CHUNK - 1) bsum[blockIdx.x] = sm[tid];
}

__global__ void k_scan2(int* __restrict__ bsum, int* __restrict__ offs) {
    __shared__ int sm[256];
    int tid = threadIdx.x;
    int x = (tid < NBLK_SCAN) ? bsum[tid] : 0;
    sm[tid] = x;
    __syncthreads();
    for (int off = 1; off < 256; off <<= 1) {
        int v = (tid >= off) ? sm[tid - off] : 0;
        __syncthreads();
        sm[tid] += v;
        __syncthreads();
    }
    if (tid < NBLK_SCAN) offs[tid] = sm[tid] - x;
}

// finalize scan; replicate into pos (removes the D2D memcpy dispatch)
__global__ void k_scan3(int* __restrict__ ptr, const int* __restrict__ offs,
                        int* __restrict__ pos) {
    int idx = blockIdx.x * blockDim.x + threadIdx.x;
    if (idx > NN) return;
    int v = ptr[idx] + offs[idx / SCAN_CHUNK];
    ptr[idx] = v;
    pos[idx] = v;
}

// fill CSR: ONE 16B record per user slot {src<<6, jit, e+1, n bits} -> a
// single random line per j1, plus item-side srcadjI[j0] and coalesced jpos1.
// (dummy user slots stay all-zero from the bulk memset: src=0, n=0)
__global__ void k_fill(const int* __restrict__ row0, const int* __restrict__ col0,
                       const float* __restrict__ dinv, int* __restrict__ pos,
                       const int* __restrict__ ptr, int4* __restrict__ urec,
                       int* __restrict__ srcadjI, int* __restrict__ jpos1) {
    int e = blockIdx.x * blockDim.x + threadIdx.x;
    if (e >= NE) return;
    int r = row0[e], c = col0[e];
    int ptrU = ptr[NUM_USER];
    int j1 = atomicAdd(&pos[r], 1);
    int j0 = atomicAdd(&pos[c], 1);
    float n = dinv[r] * dinv[c];
    urec[j1] = make_int4((c - NUM_USER) << 6, j0 - ptrU, e + 1,
                         __float_as_int(n));
    srcadjI[j0 - ptrU] = r << 6;
    jpos1[e] = j1;
}

// merged: blocks [0, NB_W0) = slot-parallel weight init from urec (COALESCED
// norm2/wu writes; Sin gathers are read-only, L3-absorbed); rest = item-node
// dummy-slot srcadjI zeros (user dummies already zero via urec memset).
__global__ void k_w0pad(const float* __restrict__ Sin, const int* __restrict__ ptr,
                        const int* __restrict__ cnt, const int4* __restrict__ urec,
                        int* __restrict__ srcadjI, float2* __restrict__ norm2,
                        float4* __restrict__ wu) {
    int b = blockIdx.x;
    if (b < NB_W0) {
        int j = b * 256 + threadIdx.x;
        if (j >= ptr[NUM_USER]) return;
        int4 u = urec[j];
        if (u.z == 0) return;   // dummy: stays zero
        int e = u.z - 1;
        float n = __int_as_float(u.w);
        float4 s = make_float4(Sin[e], Sin[NE + e], Sin[2 * NE + e], Sin[3 * NE + e]);
        float4 p = softmax4(s);
        norm2[j] = make_float2(n, 1.0f / n);
        wu[j] = make_float4(n * p.x, n * p.y, n * p.z, n * p.w);
    } else {
        int nno = NUM_USER + (b - NB_W0) * 256 + threadIdx.x;
        if (nno >= NN) return;
        int ptrU = ptr[NUM_USER];
        int v = ptr[nno];
        int d = cnt[nno];
        int end = v + ((d + 3) & ~3);
        for (int j = v + d; j < end; ++j) srcadjI[j - ptrU] = 0;
    }
}

// Scur4 (slot order, written by last conv) -> Sout [4][E] edge order
__global__ void k_sout(const float4* __restrict__ Scur4, const int* __restrict__ jpos1,
                       float* __restrict__ Sout) {
    int e = blockIdx.x * blockDim.x + threadIdx.x;
    if (e >= NE) return;
    float4 s = Scur4[jpos1[e]];
    Sout[e] = s.x;
    Sout[NE + e] = s.y;
    Sout[2 * NE + e] = s.z;
    Sout[3 * NE + e] = s.w;
}

// ---- user conv block macros: 16 outstanding gathers per issue point ----
// (src read from urec records: urec4[(j)<<2], pre-scaled by DIM)
#define UCONV16(JOFF, TP0) do { \
    int j = beg + (JOFF); \
    int s0 = urec4[(j + 0) << 2]; \
    int s1 = urec4[(j + 1) << 2]; \
    int s2 = urec4[(j + 2) << 2]; \
    int s3 = urec4[(j + 3) << 2]; \
    int s4 = urec4[(j + 4) << 2]; \
    int s5 = urec4[(j + 5) << 2]; \
    int s6 = urec4[(j + 6) << 2]; \
    int s7 = urec4[(j + 7) << 2]; \
    int s8 = urec4[(j + 8) << 2]; \
    int s9 = urec4[(j + 9) << 2]; \
    int s10 = urec4[(j + 10) << 2]; \
    int s11 = urec4[(j + 11) << 2]; \
    int s12 = urec4[(j + 12) << 2]; \
    int s13 = urec4[(j + 13) << 2]; \
    int s14 = urec4[(j + 14) << 2]; \
    int s15 = urec4[(j + 15) << 2]; \
    unsigned c0 = cmbI[s0 + lane]; \
    unsigned c1 = cmbI[s1 + lane]; \
    unsigned c2 = cmbI[s2 + lane]; \
    unsigned c3 = cmbI[s3 + lane]; \
    unsigned c4 = cmbI[s4 + lane]; \
    unsigned c5 = cmbI[s5 + lane]; \
    unsigned c6 = cmbI[s6 + lane]; \
    unsigned c7 = cmbI[s7 + lane]; \
    unsigned c8 = cmbI[s8 + lane]; \
    unsigned c9 = cmbI[s9 + lane]; \
    unsigned c10 = cmbI[s10 + lane]; \
    unsigned c11 = cmbI[s11 + lane]; \
    unsigned c12 = cmbI[s12 + lane]; \
    unsigned c13 = cmbI[s13 + lane]; \
    unsigned c14 = cmbI[s14 + lane]; \
    unsigned c15 = cmbI[s15 + lane]; \
    a0 = fmaf(wu[4 * j + k], cvt_lo(c0), a0); \
    a1 = fmaf(wu[4 * j + 4 + k], cvt_lo(c1), a1); \
    a2 = fmaf(wu[4 * j + 8 + k], cvt_lo(c2), a2); \
    a3 = fmaf(wu[4 * j + 12 + k], cvt_lo(c3), a3); \
    a0 = fmaf(wu[4 * j + 16 + k], cvt_lo(c4), a0); \
    a1 = fmaf(wu[4 * j + 20 + k], cvt_lo(c5), a1); \
    a2 = fmaf(wu[4 * j + 24 + k], cvt_lo(c6), a2); \
    a3 = fmaf(wu[4 * j + 28 + k], cvt_lo(c7), a3); \
    a0 = fmaf(wu[4 * j + 32 + k], cvt_lo(c8), a0); \
    a1 = fmaf(wu[4 * j + 36 + k], cvt_lo(c9), a1); \
    a2 = fmaf(wu[4 * j + 40 + k], cvt_lo(c10), a2); \
    a3 = fmaf(wu[4 * j + 44 + k], cvt_lo(c11), a3); \
    a0 = fmaf(wu[4 * j + 48 + k], cvt_lo(c12), a0); \
    a1 = fmaf(wu[4 * j + 52 + k], cvt_lo(c13), a1); \
    a2 = fmaf(wu[4 * j + 56 + k], cvt_lo(c14), a2); \
    a3 = fmaf(wu[4 * j + 60 + k], cvt_lo(c15), a3); \
    tp[(TP0) + 0] = packhi(c0, c1); \
    tp[(TP0) + 1] = packhi(c2, c3); \
    tp[(TP0) + 2] = packhi(c4, c5); \
    tp[(TP0) + 3] = packhi(c6, c7); \
    tp[(TP0) + 4] = packhi(c8, c9); \
    tp[(TP0) + 5] = packhi(c10, c11); \
    tp[(TP0) + 6] = packhi(c12, c13); \
    tp[(TP0) + 7] = packhi(c14, c15); \
} while (0)

#define UCONV8(JOFF, TP0) do { \
    int j = beg + (JOFF); \
    int s0 = urec4[(j + 0) << 2]; \
    int s1 = urec4[(j + 1) << 2]; \
    int s2 = urec4[(j + 2) << 2]; \
    int s3 = urec4[(j + 3) << 2]; \
    int s4 = urec4[(j + 4) << 2]; \
    int s5 = urec4[(j + 5) << 2]; \
    int s6 = urec4[(j + 6) << 2]; \
    int s7 = urec4[(j + 7) << 2]; \
    unsigned c0 = cmbI[s0 + lane]; \
    unsigned c1 = cmbI[s1 + lane]; \
    unsigned c2 = cmbI[s2 + lane]; \
    unsigned c3 = cmbI[s3 + lane]; \
    unsigned c4 = cmbI[s4 + lane]; \
    unsigned c5 = cmbI[s5 + lane]; \
    unsigned c6 = cmbI[s6 + lane]; \
    unsigned c7 = cmbI[s7 + lane]; \
    a0 = fmaf(wu[4 * j + k], cvt_lo(c0), a0); \
    a1 = fmaf(wu[4 * j + 4 + k], cvt_lo(c1), a1); \
    a2 = fmaf(wu[4 * j + 8 + k], cvt_lo(c2), a2); \
    a3 = fmaf(wu[4 * j + 12 + k], cvt_lo(c3), a3); \
    a0 = fmaf(wu[4 * j + 16 + k], cvt_lo(c4), a0); \
    a1 = fmaf(wu[4 * j + 20 + k], cvt_lo(c5), a1); \
    a2 = fmaf(wu[4 * j + 24 + k], cvt_lo(c6), a2); \
    a3 = fmaf(wu[4 * j + 28 + k], cvt_lo(c7), a3); \
    tp[(TP0) + 0] = packhi(c0, c1); \
    tp[(TP0) + 1] = packhi(c2, c3); \
    tp[(TP0) + 2] = packhi(c4, c5); \
    tp[(TP0) + 3] = packhi(c6, c7); \
} while (0)

#define UCONV4(JOFF, TP0) do { \
    int j = beg + (JOFF); \
    int s0 = urec4[(j + 0) << 2]; \
    int s1 = urec4[(j + 1) << 2]; \
    int s2 = urec4[(j + 2) << 2]; \
    int s3 = urec4[(j + 3) << 2]; \
    unsigned c0 = cmbI[s0 + lane]; \
    unsigned c1 = cmbI[s1 + lane]; \
    unsigned c2 = cmbI[s2 + lane]; \
    unsigned c3 = cmbI[s3 + lane]; \
    a0 = fmaf(wu[4 * j + k], cvt_lo(c0), a0); \
    a1 = fmaf(wu[4 * j + 4 + k], cvt_lo(c1), a1); \
    a2 = fmaf(wu[4 * j + 8 + k], cvt_lo(c2), a2); \
    a3 = fmaf(wu[4 * j + 12 + k], cvt_lo(c3), a3); \
    tp[(TP0) + 0] = packhi(c0, c1); \
    tp[(TP0) + 1] = packhi(c2, c3); \
} while (0)

// fused gather conv + routing score + S/weight update.
// wave per node; lane = dim, k = lane>>4 = factor.
// nlim: NUM_USER on non-layer-end dispatches (item conv output unused there),
// NN on layer-end. Single weight buffer each side; wi scattered when flags&8.
// flags: 1 = layer end (allemb += acc), 4 = write next ego (items: +tanh T),
// 8 = scatter wi.
__global__ __launch_bounds__(256, 4) void k_conv_score(
        const int* __restrict__ ptr, const int* __restrict__ urec4,
        const int* __restrict__ srcadjI, float* __restrict__ wu,
        float* __restrict__ wi, float* __restrict__ S4f,
        const float2* __restrict__ norm2, const unsigned short* __restrict__ egoU,
        const unsigned* __restrict__ cmbI, unsigned short* __restrict__ xnextU,
        unsigned* __restrict__ cmbNext, float* __restrict__ allemb,
        int flags, int last, int nlim) {
    int node = (blockIdx.x * blockDim.x + threadIdx.x) >> 6;
    int lane = threadIdx.x & 63;
    if (node >= nlim) return;
    int beg = __builtin_amdgcn_readfirstlane(ptr[node]);
    int end = __builtin_amdgcn_readfirstlane(ptr[node + 1]);
    int count = end - beg;
    int k = lane >> 4;
    int writeWi = flags & 8;

    float a0 = 0.0f, a1 = 0.0f, a2 = 0.0f, a3 = 0.0f;

    if (node >= NUM_USER) {
        // ---- item side: conv only, 16-deep (runs only on layer-end) ----
        int ptrU = __builtin_amdgcn_readfirstlane(ptr[NUM_USER]);
        const float* wT = wi + (size_t)4 * (beg - ptrU);
        const int* sI = srcadjI + (beg - ptrU);
        int t = 0;
        for (; t + 16 <= count; t += 16) {
            int4 sA = *(const int4*)(sI + t);
            int4 sB = *(const int4*)(sI + t + 4);
            int4 sC = *(const int4*)(sI + t + 8);
            int4 sD = *(const int4*)(sI + t + 12);
            a0 = fmaf(wT[4 * t + k], b2f(egoU[sA.x + lane]), a0);
            a1 = fmaf(wT[4 * t + 4 + k], b2f(egoU[sA.y + lane]), a1);
            a2 = fmaf(wT[4 * t + 8 + k], b2f(egoU[sA.z + lane]), a2);
            a3 = fmaf(wT[4 * t + 12 + k], b2f(egoU[sA.w + lane]), a3);
            a0 = fmaf(wT[4 * t + 16 + k], b2f(egoU[sB.x + lane]), a0);
            a1 = fmaf(wT[4 * t + 20 + k], b2f(egoU[sB.y + lane]), a1);
            a2 = fmaf(wT[4 * t + 24 + k], b2f(egoU[sB.z + lane]), a2);
            a3 = fmaf(wT[4 * t + 28 + k], b2f(egoU[sB.w + lane]), a3);
            a0 = fmaf(wT[4 * t + 32 + k], b2f(egoU[sC.x + lane]), a0);
            a1 = fmaf(wT[4 * t + 36 + k], b2f(egoU[sC.y + lane]), a1);
            a2 = fmaf(wT[4 * t + 40 + k], b2f(egoU[sC.z + lane]), a2);
            a3 = fmaf(wT[4 * t + 44 + k], b2f(egoU[sC.w + lane]), a3);
            a0 = fmaf(wT[4 * t + 48 + k], b2f(egoU[sD.x + lane]), a0);
            a1 = fmaf(wT[4 * t + 52 + k], b2f(egoU[sD.y + lane]), a1);
            a2 = fmaf(wT[4 * t + 56 + k], b2f(egoU[sD.z + lane]), a2);
            a3 = fmaf(wT[4 * t + 60 + k], b2f(egoU[sD.w + lane]), a3);
        }
        if (count & 8) {
            int4 sA = *(const int4*)(sI + t);
            int4 sB = *(const int4*)(sI + t + 4);
            a0 = fmaf(wT[4 * t + k], b2f(egoU[sA.x + lane]), a0);
            a1 = fmaf(wT[4 * t + 4 + k], b2f(egoU[sA.y + lane]), a1);
            a2 = fmaf(wT[4 * t + 8 + k], b2f(egoU[sA.z + lane]), a2);
            a3 = fmaf(wT[4 * t + 12 + k], b2f(egoU[sA.w + lane]), a3);
            a0 = fmaf(wT[4 * t + 16 + k], b2f(egoU[sB.x + lane]), a0);
            a1 = fmaf(wT[4 * t + 20 + k], b2f(egoU[sB.y + lane]), a1);
            a2 = fmaf(wT[4 * t + 24 + k], b2f(egoU[sB.z + lane]), a2);
            a3 = fmaf(wT[4 * t + 28 + k], b2f(egoU[sB.w + lane]), a3);
            t += 8;
        }
        if (count & 4) {
            int4 sA = *(const int4*)(sI + t);
            a0 = fmaf(wT[4 * t + k], b2f(egoU[sA.x + lane]), a0);
            a1 = fmaf(wT[4 * t + 4 + k], b2f(egoU[sA.y + lane]), a1);
            a2 = fmaf(wT[4 * t + 8 + k], b2f(egoU[sA.z + lane]), a2);
            a3 = fmaf(wT[4 * t + 12 + k], b2f(egoU[sA.w + lane]), a3);
        }
        float acc = (a0 + a1) + (a2 + a3);
        if (flags & 1) {
            int i = node * DIM + lane;
            allemb[i] += acc;
            if (flags & 4) {
                float ss = red16(acc * acc);
                float tt = tanhf(acc / fmaxf(sqrtf(ss), 1e-12f));
                cmbNext[i - NUM_USER * DIM] =
                    (((unsigned)f2b(tt)) << 16) | (unsigned)f2b(acc);
            }
        }
        return;
    }

    // ---- user side: conv + routing score + fused S/w update ----
    unsigned tp[22];          // packed T cache: 2 slots/word, static-indexed
    bool big = count > MAXU_SLOTS;   // wave-uniform fallback (statistically never)
    int rem = count & 15;
    int rbase = count & ~15;

    if (!big) {
        if (count >= 16) UCONV16(0, 0);
        if (count >= 32) UCONV16(16, 8);
        if (rem & 8) UCONV8(rbase, 16);
        if (rem & 4) UCONV4(rbase + (rem & 8), 20);
    } else {
        for (int j = beg; j < end; j += 4) {
            int s0 = urec4[(j + 0) << 2];
            int s1 = urec4[(j + 1) << 2];
            int s2 = urec4[(j + 2) << 2];
            int s3 = urec4[(j + 3) << 2];
            a0 = fmaf(wu[4 * j + k], cvt_lo(cmbI[s0 + lane]), a0);
            a1 = fmaf(wu[4 * j + 4 + k], cvt_lo(cmbI[s1 + lane]), a1);
            a2 = fmaf(wu[4 * j + 8 + k], cvt_lo(cmbI[s2 + lane]), a2);
            a3 = fmaf(wu[4 * j + 12 + k], cvt_lo(cmbI[s3 + lane]), a3);
        }
    }
    float acc = (a0 + a1) + (a2 + a3);

    if (flags & 1) {
        int i = node * DIM + lane;
        allemb[i] += acc;
        if (flags & 4) xnextU[i] = f2b(acc);
    }

    // routing score from register cache + fused per-slot S/weight update
    float ssu = red16(acc * acc);
    float u = acc / fmaxf(sqrtf(ssu), 1e-12f);
    bool b0 = lane & 1;
    bool b1 = lane & 2;
    bool b2 = lane & 4;
    bool b3 = lane & 8;

    if (!big) {
#define USC16(JOFF, TP0) do { \
        int j = beg + (JOFF); \
        float p0 = u * __uint_as_float(tp[(TP0) + 0] << 16); \
        float p1 = u * __uint_as_float(tp[(TP0) + 0] & 0xffff0000u); \
        float p2 = u * __uint_as_float(tp[(TP0) + 1] << 16); \
        float p3 = u * __uint_as_float(tp[(TP0) + 1] & 0xffff0000u); \
        float p4 = u * __uint_as_float(tp[(TP0) + 2] << 16); \
        float p5 = u * __uint_as_float(tp[(TP0) + 2] & 0xffff0000u); \
        float p6 = u * __uint_as_float(tp[(TP0) + 3] << 16); \
        float p7 = u * __uint_as_float(tp[(TP0) + 3] & 0xffff0000u); \
        float p8 = u * __uint_as_float(tp[(TP0) + 4] << 16); \
        float p9 = u * __uint_as_float(tp[(TP0) + 4] & 0xffff0000u); \
        float p10 = u * __uint_as_float(tp[(TP0) + 5] << 16); \
        float p11 = u * __uint_as_float(tp[(TP0) + 5] & 0xffff0000u); \
        float p12 = u * __uint_as_float(tp[(TP0) + 6] << 16); \
        float p13 = u * __uint_as_float(tp[(TP0) + 6] & 0xffff0000u); \
        float p14 = u * __uint_as_float(tp[(TP0) + 7] << 16); \
        float p15 = u * __uint_as_float(tp[(TP0) + 7] & 0xffff0000u); \
        float q0 = mixv(p0, p1, b0, 1); \
        float q1 = mixv(p2, p3, b0, 1); \
        float q2 = mixv(p4, p5, b0, 1); \
        float q3 = mixv(p6, p7, b0, 1); \
        float q4 = mixv(p8, p9, b0, 1); \
        float q5 = mixv(p10, p11, b0, 1); \
        float q6 = mixv(p12, p13, b0, 1); \
        float q7 = mixv(p14, p15, b0, 1); \
        float r0 = mixv(q0, q1, b1, 2); \
        float r1 = mixv(q2, q3, b1, 2); \
        float r2 = mixv(q4, q5, b1, 2); \
        float r3 = mixv(q6, q7, b1, 2); \
        float s0 = mixv(r0, r1, b2, 4); \
        float s1 = mixv(r2, r3, b2, 4); \
        float t0 = mixv(s0, s1, b3, 8); \
        fused_upd(j + (lane & 15), k, t0, true, \
                  wu, S4f, norm2, urec4, wi, last, writeWi); \
} while (0)
        if (count >= 16) USC16(0, 0);
        if (count >= 32) USC16(16, 8);
        if (rem & 8) {
            int j = beg + rbase;
            float p0 = u * __uint_as_float(tp[16] << 16);
            float p1 = u * __uint_as_float(tp[16] & 0xffff0000u);
            float p2 = u * __uint_as_float(tp[17] << 16);
            float p3 = u * __uint_as_float(tp[17] & 0xffff0000u);
            float p4 = u * __uint_as_float(tp[18] << 16);
            float p5 = u * __uint_as_float(tp[18] & 0xffff0000u);
            float p6 = u * __uint_as_float(tp[19] << 16);
            float p7 = u * __uint_as_float(tp[19] & 0xffff0000u);
            float q0 = mixv(p0, p1, b0, 1);
            float q1 = mixv(p2, p3, b0, 1);
            float q2 = mixv(p4, p5, b0, 1);
            float q3 = mixv(p6, p7, b0, 1);
            float r0 = mixv(q0, q1, b1, 2);
            float r1 = mixv(q2, q3, b1, 2);
            float t0 = mixv(r0, r1, b2, 4);
            t0 += __shfl_xor(t0, 8);
            fused_upd(j + (lane & 7), k, t0, !(lane & 8),
                      wu, S4f, norm2, urec4, wi, last, writeWi);
        }
        if (rem & 4) {
            int j = beg + rbase + (rem & 8);
            float p0 = u * __uint_as_float(tp[20] << 16);
            float p1 = u * __uint_as_float(tp[20] & 0xffff0000u);
            float p2 = u * __uint_as_float(tp[21] << 16);
            float p3 = u * __uint_as_float(tp[21] & 0xffff0000u);
            float q0 = mixv(p0, p1, b0, 1);
            float q1 = mixv(p2, p3, b0, 1);
            float r0 = mixv(q0, q1, b1, 2);
            r0 += __shfl_xor(r0, 4);
            r0 += __shfl_xor(r0, 8);
            fused_upd(j + (lane & 3), k, r0, !(lane & 12),
                      wu, S4f, norm2, urec4, wi, last, writeWi);
        }
    } else {
        for (int j = beg; j < end; j += 4) {
            int s0 = urec4[(j + 0) << 2];
            int s1 = urec4[(j + 1) << 2];
            int s2 = urec4[(j + 2) << 2];
            int s3 = urec4[(j + 3) << 2];
            float p0 = red16(u * cvt_hi(cmbI[s0 + lane]));
            float p1 = red16(u * cvt_hi(cmbI[s1 + lane]));
            float p2 = red16(u * cvt_hi(cmbI[s2 + lane]));
            float p3 = red16(u * cvt_hi(cmbI[s3 + lane]));
            int sl = lane & 3;
            float dv = p0;
            dv = (sl == 1) ? p1 : dv;
            dv = (sl == 2) ? p2 : dv;
            dv = (sl == 3) ? p3 : dv;
            fused_upd(j + sl, k, dv, !(lane & 12),
                      wu, S4f, norm2, urec4, wi, last, writeWi);
        }
    }
}

extern "C" void kernel_launch(void* const* d_in, const int* in_sizes, int n_in,
                              void* d_out, int out_size, void* d_ws, size_t ws_size,
                              hipStream_t stream) {
    const float* user = (const float*)d_in[0];
    const float* item = (const float*)d_in[1];
    const float* S_in = (const float*)d_in[2];
    const int* edge = (const int*)d_in[3];
    const int* row0 = edge;
    const int* col0 = edge + NE;

    float* out = (float*)d_out;
    float* allemb = out;              // NN*DIM floats
    float* Sfinal = out + NN * DIM;   // KF*NE floats

    char* ws = (char*)d_ws;
    size_t off = 0;
    auto carve = [&](size_t bytes) { void* p = ws + off; off += (bytes + 255) & ~(size_t)255; return p; };
    int* ptr = (int*)carve((NN + 1) * sizeof(int));
    int* pos = (int*)carve((NN + 1) * sizeof(int));
    int* bsum = (int*)carve(256 * sizeof(int));
    int* offs = (int*)carve(256 * sizeof(int));
    int* srcadjI = (int*)carve((size_t)NEPI_MAX * sizeof(int));
    int* jpos1 = (int*)carve((size_t)NE * sizeof(int));
    float* dinv = (float*)carve(NN * sizeof(float));
    float4* Scur4 = (float4*)carve((size_t)NEPU_MAX * sizeof(float4));
    // contiguous zero-region: cnt | urec | norm2 | wu | wi  (ONE bulk memset)
    size_t zbeg = off;
    int* cnt = (int*)carve((NN + 1) * sizeof(int));
    int4* urec = (int4*)carve((size_t)NEPU_MAX * sizeof(int4));
    float2* norm2 = (float2*)carve((size_t)NEPU_MAX * sizeof(float2));
    float4* wu = (float4*)carve((size_t)NEPU_MAX * sizeof(float4));
    float4* wi = (float4*)carve((size_t)NEPI_MAX * sizeof(float4));
    size_t zlen = off - zbeg;
    unsigned short* egoUA = (unsigned short*)carve((size_t)NUM_USER * DIM * 2);
    unsigned short* egoUB = (unsigned short*)carve((size_t)NUM_USER * DIM * 2);
    unsigned* cmbIA = (unsigned*)carve((size_t)NUM_ITEM * DIM * 4);
    unsigned* cmbIB = (unsigned*)carve((size_t)NUM_ITEM * DIM * 4);

    hipMemsetAsync(ws + zbeg, 0, zlen, stream);

    k_setup<<<NB_SETUP, 256, 0, stream>>>(user, item, egoUA, cmbIA, allemb,
                                          row0, col0, cnt);
    k_scan1<<<NBLK_SCAN, SCAN_CHUNK, 0, stream>>>(cnt, dinv, ptr, bsum);
    k_scan2<<<1, 256, 0, stream>>>(bsum, offs);
    k_scan3<<<(NN + 1 + 255) / 256, 256, 0, stream>>>(ptr, offs, pos);
    k_fill<<<(NE + 255) / 256, 256, 0, stream>>>(row0, col0, dinv, pos, ptr,
                                                 urec, srcadjI, jpos1);
    k_w0pad<<<NB_W0 + NB_PADI, 256, 0, stream>>>(S_in, ptr, cnt, urec, srcadjI,
                                                 norm2, wu);

    unsigned short* egoU = egoUA;
    unsigned short* egoUn = egoUB;
    unsigned* cmbI = cmbIA;
    unsigned* cmbIn = cmbIB;
    for (int layer = 0; layer < 2; ++layer) {
        for (int it = 0; it < 2; ++it) {
            int flags = 0;
            if (it == 0) flags |= 8;                   // scatter wi (consumed at it=1)
            if (it == 1) flags |= 1;                   // layer end: allemb += acc
            if (it == 1 && layer == 0) flags |= 4;     // write next ego (+item T)
            int last = (layer == 1 && it == 1) ? 1 : 0;
            // non-layer-end: item x_new is never consumed -> user-only grid
            int nlim = (it == 1) ? NN : NUM_USER;
            k_conv_score<<<(nlim * 64 + 255) / 256, 256, 0, stream>>>(
                ptr, (const int*)urec, srcadjI, (float*)wu, (float*)wi,
                (float*)Scur4, norm2, egoU, cmbI, egoUn, cmbIn, allemb,
                flags, last, nlim);
        }
        unsigned short* t = egoU; egoU = egoUn; egoUn = t;
        unsigned* tc = cmbI; cmbI = cmbIn; cmbIn = tc;
    }
    k_sout<<<(NE + 255) / 256, 256, 0, stream>>>(Scur4, jpos1, Sfinal);
}

// Round 11
// 374.712 us; speedup vs baseline: 1.0552x; 1.0552x over previous
//
#include <hip/hip_runtime.h>

#define NUM_USER 60000
#define NUM_ITEM 40000
#define NN 100000
#define NE 500000
#define DIM 64
#define KF 4
#define SCAN_CHUNK 512
#define NBLK_SCAN ((NN + 1 + SCAN_CHUNK - 1) / SCAN_CHUNK)
// padded slot-count upper bounds (each node rounds up to multiple of 4)
#define NEPU_MAX (NE + 3 * NUM_USER)   // 680000 user-side slots max
#define NEPI_MAX (NE + 3 * NUM_ITEM)   // 620000 item-side slots max
#define NSLOT_MAX (NEPU_MAX + NEPI_MAX)
#define MAXU_SLOTS 44                  // register-cached user path handles <=44 slots
#define NB_U4 (NUM_USER * DIM / 4 / 256)   // 3750 user-init blocks (float4/thread)
#define NB_I (NUM_ITEM / 16)               // 2500 item-init blocks (16 nodes/block)
#define NB_SETUP (NB_U4 + NB_I)            // 6250
#define EPB (NE / NB_SETUP)                // 80 edges counted per setup block

// sum within each 16-lane group (butterfly: all lanes get result)
__device__ __forceinline__ float red16(float v) {
    v += __shfl_xor(v, 1);
    v += __shfl_xor(v, 2);
    v += __shfl_xor(v, 4);
    v += __shfl_xor(v, 8);
    return v;
}

__device__ __forceinline__ float b2f(unsigned short u) {
    return __uint_as_float(((unsigned)u) << 16);
}
__device__ __forceinline__ unsigned short f2b(float x) {
    unsigned u = __float_as_uint(x);
    u = (u + 0x7fffu + ((u >> 16) & 1u)) >> 16;   // RNE
    return (unsigned short)u;
}
// combined item word: high16 = T (bf16 bits), low16 = ego (bf16 bits)
__device__ __forceinline__ float cvt_lo(unsigned c) { return __uint_as_float(c << 16); }
__device__ __forceinline__ float cvt_hi(unsigned c) { return __uint_as_float(c & 0xffff0000u); }
// pack hi16 halves of two combined words: lo16(out)=hi16(c0), hi16(out)=hi16(c1)
__device__ __forceinline__ unsigned packhi(unsigned c0, unsigned c1) {
#if defined(__has_builtin) && __has_builtin(__builtin_amdgcn_perm)
    return __builtin_amdgcn_perm(c1, c0, 0x07060302u);
#else
    return (c0 >> 16) | (c1 & 0xffff0000u);
#endif
}
// mixed-butterfly level: lane keeps the value whose slot-bit matches its lane bit
__device__ __forceinline__ float mixv(float x, float y, bool b, int m) {
    return (b ? y : x) + __shfl_xor(b ? x : y, m);
}

__device__ __forceinline__ float4 softmax4(float4 s) {
    float m = fmaxf(fmaxf(s.x, s.y), fmaxf(s.z, s.w));
    float e0 = __expf(s.x - m), e1 = __expf(s.y - m);
    float e2 = __expf(s.z - m), e3 = __expf(s.w - m);
    float inv = 1.0f / (e0 + e1 + e2 + e3);
    return make_float4(e0 * inv, e1 * inv, e2 * inv, e3 * inv);
}

// Per-user-slot 32B record: [0]=src<<6 [1]=jit(item-local) [2]=n [3]=1/n [4..7]=w
// Dummy slots: all-zero from bulk memset (src=0, n=0 -> update skipped).
#define R_SRC(j)  reci[8 * (j) + 0]
#define R_JIT(j)  reci[8 * (j) + 1]
#define R_N(j)    recf[8 * (j) + 2]
#define R_RN(j)   recf[8 * (j) + 3]
#define R_W(j, k) recf[8 * (j) + 4 + (k)]

// Fused per-slot S/weight update. softmax(S_old) reconstructed as w*(1/n)
// (record is L1-hot from the conv loop). snew = w*rn + dot.
// last: S4f <- snew (final output); else w' = n*softmax_k(snew) -> record
// (+ wi item-order scatter only when writeWi; it=1's wi is never consumed).
__device__ __forceinline__ void fused_upd(int jj, int k, float dot, bool wr,
        const int* __restrict__ reci, float* __restrict__ recf,
        float* __restrict__ S4f, float* __restrict__ wiW, int last, int writeWi) {
    float w = R_W(jj, k);
    float n = R_N(jj);
    float rn = R_RN(jj);
    float snew = fmaf(w, rn, dot);
    if (last) {
        if (wr) S4f[4 * jj + k] = snew;
        return;
    }
    float m2 = fmaxf(snew, __shfl_xor(snew, 16));
    m2 = fmaxf(m2, __shfl_xor(m2, 32));
    float e2 = __expf(snew - m2);
    float s2 = e2 + __shfl_xor(e2, 16);
    s2 += __shfl_xor(s2, 32);
    if (wr && n > 0.0f) {
        float wn = n * e2 * (1.0f / s2);
        R_W(jj, k) = wn;
        if (writeWi) wiW[4 * R_JIT(jj) + k] = wn;
    }
}

// init (vectorized 4 dims/thread) + DISTRIBUTED degree count (80 edges/block,
// threads 0..159 one endpoint each -- atomics hide under the streaming init).
__global__ void k_setup(const float* __restrict__ user, const float* __restrict__ item,
                        unsigned short* __restrict__ egoU, unsigned* __restrict__ cmbI,
                        float* __restrict__ allemb, const int* __restrict__ row0,
                        const int* __restrict__ col0, int* __restrict__ cnt) {
    int b = blockIdx.x, t = threadIdx.x;
    int ebase = b * EPB;
    if (t < EPB) atomicAdd(&cnt[row0[ebase + t]], 1);
    else if (t < 2 * EPB) atomicAdd(&cnt[col0[ebase + t - EPB]], 1);
    if (b < NB_U4) {
        // user: pure streaming copy, float4/thread
        int idx = (b * 256 + t) * 4;
        float4 v = *(const float4*)(user + idx);
        ushort4 e;
        e.x = f2b(v.x); e.y = f2b(v.y); e.z = f2b(v.z); e.w = f2b(v.w);
        *(ushort4*)(egoU + idx) = e;
        *(float4*)(allemb + idx) = v;
    } else {
        // item: 16 lanes/node, float4/lane; 16-dim norm = 4-lane reduce
        int bb = b - NB_U4;
        int lane = t & 63;
        int nodeI = bb * 16 + ((t >> 6) << 2) + (lane >> 4);
        int idx = nodeI * DIM + (lane & 15) * 4;
        float4 v = *(const float4*)(item + idx);
        float ss = v.x * v.x + v.y * v.y + v.z * v.z + v.w * v.w;
        ss += __shfl_xor(ss, 1);
        ss += __shfl_xor(ss, 2);
        float rinv = 1.0f / fmaxf(sqrtf(ss), 1e-12f);
        uint4 o;
        o.x = (((unsigned)f2b(tanhf(v.x * rinv))) << 16) | (unsigned)f2b(v.x);
        o.y = (((unsigned)f2b(tanhf(v.y * rinv))) << 16) | (unsigned)f2b(v.y);
        o.z = (((unsigned)f2b(tanhf(v.z * rinv))) << 16) | (unsigned)f2b(v.z);
        o.w = (((unsigned)f2b(tanhf(v.w * rinv))) << 16) | (unsigned)f2b(v.w);
        *(uint4*)(cmbI + idx) = o;
        *(float4*)(allemb + NUM_USER * DIM + idx) = v;
    }
}

// --- 3-stage exclusive scan over padded counts -> ptr[NN+1]; dinv fused ---
__global__ void k_scan1(const int* __restrict__ cnt, float* __restrict__ dinv,
                        int* __restrict__ ptr, int* __restrict__ bsum) {
    __shared__ int sm[SCAN_CHUNK];
    int tid = threadIdx.x;
    int idx = blockIdx.x * SCAN_CHUNK + tid;
    int d = (idx < NN) ? cnt[idx] : 0;
    if (idx < NN) dinv[idx] = (d > 0) ? rsqrtf((float)d) : 0.0f;
    int x = (d + 3) & ~3;
    sm[tid] = x;
    __syncthreads();
    for (int off = 1; off < SCAN_CHUNK; off <<= 1) {
        int v = (tid >= off) ? sm[tid - off] : 0;
        __syncthreads();
        sm[tid] += v;
        __syncthreads();
    }
    if (idx <= NN) ptr[idx] = sm[tid] - x;
    if (tid == SCAN_CHUNK - 1) bsum[blockIdx.x] = sm[tid];
}

__global__ void k_scan2(int* __restrict__ bsum, int* __restrict__ offs) {
    __shared__ int sm[256];
    int tid = threadIdx.x;
    int x = (tid < NBLK_SCAN) ? bsum[tid] : 0;
    sm[tid] = x;
    __syncthreads();
    for (int off = 1; off < 256; off <<= 1) {
        int v = (tid >= off) ? sm[tid - off] : 0;
        __syncthreads();
        sm[tid] += v;
        __syncthreads();
    }
    if (tid < NBLK_SCAN) offs[tid] = sm[tid] - x;
}

// finalize scan; replicate into pos; zero item-node dummy srcadjI slots
// (srcadjI is GLOBAL-slot-indexed so no ptrU needed; user dummies live in
// rec8, zeroed by the bulk memset)
__global__ void k_scan3(int* __restrict__ ptr, const int* __restrict__ offs,
                        int* __restrict__ pos, const int* __restrict__ cnt,
                        int* __restrict__ srcadjI) {
    int idx = blockIdx.x * blockDim.x + threadIdx.x;
    if (idx > NN) return;
    int v = ptr[idx] + offs[idx / SCAN_CHUNK];
    ptr[idx] = v;
    pos[idx] = v;
    if (idx >= NUM_USER && idx < NN) {
        int d = cnt[idx];
        int end = v + ((d + 3) & ~3);
        for (int j = v + d; j < end; ++j) srcadjI[j] = 0;
    }
}

// fill CSR + w0 in ONE pass: thread owns edge e; user side writes a single
// 32B record line {src,jit,n,1/n,w[4]} (coalesced Sin reads for softmax);
// item side writes srcadjI[j0] (global-slot indexed); jpos1 coalesced.
__global__ void k_fillw0(const int* __restrict__ row0, const int* __restrict__ col0,
                         const float* __restrict__ Sin, const float* __restrict__ dinv,
                         int* __restrict__ pos, const int* __restrict__ ptr,
                         int4* __restrict__ rec4, int* __restrict__ srcadjI,
                         int* __restrict__ jpos1) {
    int e = blockIdx.x * blockDim.x + threadIdx.x;
    if (e >= NE) return;
    int r = row0[e], c = col0[e];
    int ptrU = ptr[NUM_USER];
    int j1 = atomicAdd(&pos[r], 1);
    int j0 = atomicAdd(&pos[c], 1);
    float n = dinv[r] * dinv[c];
    float4 s = make_float4(Sin[e], Sin[NE + e], Sin[2 * NE + e], Sin[3 * NE + e]);
    float4 p = softmax4(s);
    int4 ra = make_int4((c - NUM_USER) << 6, j0 - ptrU,
                        __float_as_int(n), __float_as_int(1.0f / n));
    int4 rb = make_int4(__float_as_int(n * p.x), __float_as_int(n * p.y),
                        __float_as_int(n * p.z), __float_as_int(n * p.w));
    rec4[2 * j1] = ra;         // same 32B-aligned line
    rec4[2 * j1 + 1] = rb;
    srcadjI[j0] = r << 6;
    jpos1[e] = j1;
}

// Scur4 (slot order, written by last conv) -> Sout [4][E] edge order
__global__ void k_sout(const float4* __restrict__ Scur4, const int* __restrict__ jpos1,
                       float* __restrict__ Sout) {
    int e = blockIdx.x * blockDim.x + threadIdx.x;
    if (e >= NE) return;
    float4 s = Scur4[jpos1[e]];
    Sout[e] = s.x;
    Sout[NE + e] = s.y;
    Sout[2 * NE + e] = s.z;
    Sout[3 * NE + e] = s.w;
}

// ---- user conv block macros: 16 outstanding gathers per issue point ----
// (src and weights read from the per-slot record; src pre-scaled by DIM)
#define UCONV16(JOFF, TP0) do { \
    int j = beg + (JOFF); \
    int s0 = R_SRC(j + 0); \
    int s1 = R_SRC(j + 1); \
    int s2 = R_SRC(j + 2); \
    int s3 = R_SRC(j + 3); \
    int s4 = R_SRC(j + 4); \
    int s5 = R_SRC(j + 5); \
    int s6 = R_SRC(j + 6); \
    int s7 = R_SRC(j + 7); \
    int s8 = R_SRC(j + 8); \
    int s9 = R_SRC(j + 9); \
    int s10 = R_SRC(j + 10); \
    int s11 = R_SRC(j + 11); \
    int s12 = R_SRC(j + 12); \
    int s13 = R_SRC(j + 13); \
    int s14 = R_SRC(j + 14); \
    int s15 = R_SRC(j + 15); \
    unsigned c0 = cmbI[s0 + lane]; \
    unsigned c1 = cmbI[s1 + lane]; \
    unsigned c2 = cmbI[s2 + lane]; \
    unsigned c3 = cmbI[s3 + lane]; \
    unsigned c4 = cmbI[s4 + lane]; \
    unsigned c5 = cmbI[s5 + lane]; \
    unsigned c6 = cmbI[s6 + lane]; \
    unsigned c7 = cmbI[s7 + lane]; \
    unsigned c8 = cmbI[s8 + lane]; \
    unsigned c9 = cmbI[s9 + lane]; \
    unsigned c10 = cmbI[s10 + lane]; \
    unsigned c11 = cmbI[s11 + lane]; \
    unsigned c12 = cmbI[s12 + lane]; \
    unsigned c13 = cmbI[s13 + lane]; \
    unsigned c14 = cmbI[s14 + lane]; \
    unsigned c15 = cmbI[s15 + lane]; \
    a0 = fmaf(R_W(j + 0, k), cvt_lo(c0), a0); \
    a1 = fmaf(R_W(j + 1, k), cvt_lo(c1), a1); \
    a2 = fmaf(R_W(j + 2, k), cvt_lo(c2), a2); \
    a3 = fmaf(R_W(j + 3, k), cvt_lo(c3), a3); \
    a0 = fmaf(R_W(j + 4, k), cvt_lo(c4), a0); \
    a1 = fmaf(R_W(j + 5, k), cvt_lo(c5), a1); \
    a2 = fmaf(R_W(j + 6, k), cvt_lo(c6), a2); \
    a3 = fmaf(R_W(j + 7, k), cvt_lo(c7), a3); \
    a0 = fmaf(R_W(j + 8, k), cvt_lo(c8), a0); \
    a1 = fmaf(R_W(j + 9, k), cvt_lo(c9), a1); \
    a2 = fmaf(R_W(j + 10, k), cvt_lo(c10), a2); \
    a3 = fmaf(R_W(j + 11, k), cvt_lo(c11), a3); \
    a0 = fmaf(R_W(j + 12, k), cvt_lo(c12), a0); \
    a1 = fmaf(R_W(j + 13, k), cvt_lo(c13), a1); \
    a2 = fmaf(R_W(j + 14, k), cvt_lo(c14), a2); \
    a3 = fmaf(R_W(j + 15, k), cvt_lo(c15), a3); \
    tp[(TP0) + 0] = packhi(c0, c1); \
    tp[(TP0) + 1] = packhi(c2, c3); \
    tp[(TP0) + 2] = packhi(c4, c5); \
    tp[(TP0) + 3] = packhi(c6, c7); \
    tp[(TP0) + 4] = packhi(c8, c9); \
    tp[(TP0) + 5] = packhi(c10, c11); \
    tp[(TP0) + 6] = packhi(c12, c13); \
    tp[(TP0) + 7] = packhi(c14, c15); \
} while (0)

#define UCONV8(JOFF, TP0) do { \
    int j = beg + (JOFF); \
    int s0 = R_SRC(j + 0); \
    int s1 = R_SRC(j + 1); \
    int s2 = R_SRC(j + 2); \
    int s3 = R_SRC(j + 3); \
    int s4 = R_SRC(j + 4); \
    int s5 = R_SRC(j + 5); \
    int s6 = R_SRC(j + 6); \
    int s7 = R_SRC(j + 7); \
    unsigned c0 = cmbI[s0 + lane]; \
    unsigned c1 = cmbI[s1 + lane]; \
    unsigned c2 = cmbI[s2 + lane]; \
    unsigned c3 = cmbI[s3 + lane]; \
    unsigned c4 = cmbI[s4 + lane]; \
    unsigned c5 = cmbI[s5 + lane]; \
    unsigned c6 = cmbI[s6 + lane]; \
    unsigned c7 = cmbI[s7 + lane]; \
    a0 = fmaf(R_W(j + 0, k), cvt_lo(c0), a0); \
    a1 = fmaf(R_W(j + 1, k), cvt_lo(c1), a1); \
    a2 = fmaf(R_W(j + 2, k), cvt_lo(c2), a2); \
    a3 = fmaf(R_W(j + 3, k), cvt_lo(c3), a3); \
    a0 = fmaf(R_W(j + 4, k), cvt_lo(c4), a0); \
    a1 = fmaf(R_W(j + 5, k), cvt_lo(c5), a1); \
    a2 = fmaf(R_W(j + 6, k), cvt_lo(c6), a2); \
    a3 = fmaf(R_W(j + 7, k), cvt_lo(c7), a3); \
    tp[(TP0) + 0] = packhi(c0, c1); \
    tp[(TP0) + 1] = packhi(c2, c3); \
    tp[(TP0) + 2] = packhi(c4, c5); \
    tp[(TP0) + 3] = packhi(c6, c7); \
} while (0)

#define UCONV4(JOFF, TP0) do { \
    int j = beg + (JOFF); \
    int s0 = R_SRC(j + 0); \
    int s1 = R_SRC(j + 1); \
    int s2 = R_SRC(j + 2); \
    int s3 = R_SRC(j + 3); \
    unsigned c0 = cmbI[s0 + lane]; \
    unsigned c1 = cmbI[s1 + lane]; \
    unsigned c2 = cmbI[s2 + lane]; \
    unsigned c3 = cmbI[s3 + lane]; \
    a0 = fmaf(R_W(j + 0, k), cvt_lo(c0), a0); \
    a1 = fmaf(R_W(j + 1, k), cvt_lo(c1), a1); \
    a2 = fmaf(R_W(j + 2, k), cvt_lo(c2), a2); \
    a3 = fmaf(R_W(j + 3, k), cvt_lo(c3), a3); \
    tp[(TP0) + 0] = packhi(c0, c1); \
    tp[(TP0) + 1] = packhi(c2, c3); \
} while (0)

// fused gather conv + routing score + S/weight update.
// wave per node; lane = dim, k = lane>>4 = factor.
// nlim: NUM_USER on non-layer-end dispatches (item conv output unused there),
// NN on layer-end. Per-slot record holds src/jit/n/weights (one cache line
// per 2 slots); wi scattered only when flags&8 (it=0 dispatches).
// flags: 1 = layer end (allemb += acc), 4 = write next ego (items: +tanh T),
// 8 = scatter wi.
__global__ __launch_bounds__(256, 4) void k_conv_score(
        const int* __restrict__ ptr, const int* __restrict__ reci,
        float* __restrict__ recf, const int* __restrict__ srcadjI,
        float* __restrict__ wi, float* __restrict__ S4f,
        const unsigned short* __restrict__ egoU, const unsigned* __restrict__ cmbI,
        unsigned short* __restrict__ xnextU, unsigned* __restrict__ cmbNext,
        float* __restrict__ allemb, int flags, int last, int nlim) {
    int node = (blockIdx.x * blockDim.x + threadIdx.x) >> 6;
    int lane = threadIdx.x & 63;
    if (node >= nlim) return;
    int beg = __builtin_amdgcn_readfirstlane(ptr[node]);
    int end = __builtin_amdgcn_readfirstlane(ptr[node + 1]);
    int count = end - beg;
    int k = lane >> 4;
    int writeWi = flags & 8;

    float a0 = 0.0f, a1 = 0.0f, a2 = 0.0f, a3 = 0.0f;

    if (node >= NUM_USER) {
        // ---- item side: conv only, 16-deep (runs only on layer-end) ----
        int ptrU = __builtin_amdgcn_readfirstlane(ptr[NUM_USER]);
        const float* wT = wi + (size_t)4 * (beg - ptrU);
        const int* sI = srcadjI + beg;
        int t = 0;
        for (; t + 16 <= count; t += 16) {
            int4 sA = *(const int4*)(sI + t);
            int4 sB = *(const int4*)(sI + t + 4);
            int4 sC = *(const int4*)(sI + t + 8);
            int4 sD = *(const int4*)(sI + t + 12);
            a0 = fmaf(wT[4 * t + k], b2f(egoU[sA.x + lane]), a0);
            a1 = fmaf(wT[4 * t + 4 + k], b2f(egoU[sA.y + lane]), a1);
            a2 = fmaf(wT[4 * t + 8 + k], b2f(egoU[sA.z + lane]), a2);
            a3 = fmaf(wT[4 * t + 12 + k], b2f(egoU[sA.w + lane]), a3);
            a0 = fmaf(wT[4 * t + 16 + k], b2f(egoU[sB.x + lane]), a0);
            a1 = fmaf(wT[4 * t + 20 + k], b2f(egoU[sB.y + lane]), a1);
            a2 = fmaf(wT[4 * t + 24 + k], b2f(egoU[sB.z + lane]), a2);
            a3 = fmaf(wT[4 * t + 28 + k], b2f(egoU[sB.w + lane]), a3);
            a0 = fmaf(wT[4 * t + 32 + k], b2f(egoU[sC.x + lane]), a0);
            a1 = fmaf(wT[4 * t + 36 + k], b2f(egoU[sC.y + lane]), a1);
            a2 = fmaf(wT[4 * t + 40 + k], b2f(egoU[sC.z + lane]), a2);
            a3 = fmaf(wT[4 * t + 44 + k], b2f(egoU[sC.w + lane]), a3);
            a0 = fmaf(wT[4 * t + 48 + k], b2f(egoU[sD.x + lane]), a0);
            a1 = fmaf(wT[4 * t + 52 + k], b2f(egoU[sD.y + lane]), a1);
            a2 = fmaf(wT[4 * t + 56 + k], b2f(egoU[sD.z + lane]), a2);
            a3 = fmaf(wT[4 * t + 60 + k], b2f(egoU[sD.w + lane]), a3);
        }
        if (count & 8) {
            int4 sA = *(const int4*)(sI + t);
            int4 sB = *(const int4*)(sI + t + 4);
            a0 = fmaf(wT[4 * t + k], b2f(egoU[sA.x + lane]), a0);
            a1 = fmaf(wT[4 * t + 4 + k], b2f(egoU[sA.y + lane]), a1);
            a2 = fmaf(wT[4 * t + 8 + k], b2f(egoU[sA.z + lane]), a2);
            a3 = fmaf(wT[4 * t + 12 + k], b2f(egoU[sA.w + lane]), a3);
            a0 = fmaf(wT[4 * t + 16 + k], b2f(egoU[sB.x + lane]), a0);
            a1 = fmaf(wT[4 * t + 20 + k], b2f(egoU[sB.y + lane]), a1);
            a2 = fmaf(wT[4 * t + 24 + k], b2f(egoU[sB.z + lane]), a2);
            a3 = fmaf(wT[4 * t + 28 + k], b2f(egoU[sB.w + lane]), a3);
            t += 8;
        }
        if (count & 4) {
            int4 sA = *(const int4*)(sI + t);
            a0 = fmaf(wT[4 * t + k], b2f(egoU[sA.x + lane]), a0);
            a1 = fmaf(wT[4 * t + 4 + k], b2f(egoU[sA.y + lane]), a1);
            a2 = fmaf(wT[4 * t + 8 + k], b2f(egoU[sA.z + lane]), a2);
            a3 = fmaf(wT[4 * t + 12 + k], b2f(egoU[sA.w + lane]), a3);
        }
        float acc = (a0 + a1) + (a2 + a3);
        if (flags & 1) {
            int i = node * DIM + lane;
            allemb[i] += acc;
            if (flags & 4) {
                float ss = red16(acc * acc);
                float tt = tanhf(acc / fmaxf(sqrtf(ss), 1e-12f));
                cmbNext[i - NUM_USER * DIM] =
                    (((unsigned)f2b(tt)) << 16) | (unsigned)f2b(acc);
            }
        }
        return;
    }

    // ---- user side: conv + routing score + fused S/w update ----
    unsigned tp[22];          // packed T cache: 2 slots/word, static-indexed
    bool big = count > MAXU_SLOTS;   // wave-uniform fallback (statistically never)
    int rem = count & 15;
    int rbase = count & ~15;

    if (!big) {
        if (count >= 16) UCONV16(0, 0);
        if (count >= 32) UCONV16(16, 8);
        if (rem & 8) UCONV8(rbase, 16);
        if (rem & 4) UCONV4(rbase + (rem & 8), 20);
    } else {
        for (int j = beg; j < end; j += 4) {
            int s0 = R_SRC(j + 0);
            int s1 = R_SRC(j + 1);
            int s2 = R_SRC(j + 2);
            int s3 = R_SRC(j + 3);
            a0 = fmaf(R_W(j + 0, k), cvt_lo(cmbI[s0 + lane]), a0);
            a1 = fmaf(R_W(j + 1, k), cvt_lo(cmbI[s1 + lane]), a1);
            a2 = fmaf(R_W(j + 2, k), cvt_lo(cmbI[s2 + lane]), a2);
            a3 = fmaf(R_W(j + 3, k), cvt_lo(cmbI[s3 + lane]), a3);
        }
    }
    float acc = (a0 + a1) + (a2 + a3);

    if (flags & 1) {
        int i = node * DIM + lane;
        allemb[i] += acc;
        if (flags & 4) xnextU[i] = f2b(acc);
    }

    // routing score from register cache + fused per-slot S/weight update
    float ssu = red16(acc * acc);
    float u = acc / fmaxf(sqrtf(ssu), 1e-12f);
    bool b0 = lane & 1;
    bool b1 = lane & 2;
    bool b2 = lane & 4;
    bool b3 = lane & 8;

    if (!big) {
#define USC16(JOFF, TP0) do { \
        int j = beg + (JOFF); \
        float p0 = u * __uint_as_float(tp[(TP0) + 0] << 16); \
        float p1 = u * __uint_as_float(tp[(TP0) + 0] & 0xffff0000u); \
        float p2 = u * __uint_as_float(tp[(TP0) + 1] << 16); \
        float p3 = u * __uint_as_float(tp[(TP0) + 1] & 0xffff0000u); \
        float p4 = u * __uint_as_float(tp[(TP0) + 2] << 16); \
        float p5 = u * __uint_as_float(tp[(TP0) + 2] & 0xffff0000u); \
        float p6 = u * __uint_as_float(tp[(TP0) + 3] << 16); \
        float p7 = u * __uint_as_float(tp[(TP0) + 3] & 0xffff0000u); \
        float p8 = u * __uint_as_float(tp[(TP0) + 4] << 16); \
        float p9 = u * __uint_as_float(tp[(TP0) + 4] & 0xffff0000u); \
        float p10 = u * __uint_as_float(tp[(TP0) + 5] << 16); \
        float p11 = u * __uint_as_float(tp[(TP0) + 5] & 0xffff0000u); \
        float p12 = u * __uint_as_float(tp[(TP0) + 6] << 16); \
        float p13 = u * __uint_as_float(tp[(TP0) + 6] & 0xffff0000u); \
        float p14 = u * __uint_as_float(tp[(TP0) + 7] << 16); \
        float p15 = u * __uint_as_float(tp[(TP0) + 7] & 0xffff0000u); \
        float q0 = mixv(p0, p1, b0, 1); \
        float q1 = mixv(p2, p3, b0, 1); \
        float q2 = mixv(p4, p5, b0, 1); \
        float q3 = mixv(p6, p7, b0, 1); \
        float q4 = mixv(p8, p9, b0, 1); \
        float q5 = mixv(p10, p11, b0, 1); \
        float q6 = mixv(p12, p13, b0, 1); \
        float q7 = mixv(p14, p15, b0, 1); \
        float r0 = mixv(q0, q1, b1, 2); \
        float r1 = mixv(q2, q3, b1, 2); \
        float r2 = mixv(q4, q5, b1, 2); \
        float r3 = mixv(q6, q7, b1, 2); \
        float s0 = mixv(r0, r1, b2, 4); \
        float s1 = mixv(r2, r3, b2, 4); \
        float t0 = mixv(s0, s1, b3, 8); \
        fused_upd(j + (lane & 15), k, t0, true, \
                  reci, recf, S4f, wi, last, writeWi); \
} while (0)
        if (count >= 16) USC16(0, 0);
        if (count >= 32) USC16(16, 8);
        if (rem & 8) {
            int j = beg + rbase;
            float p0 = u * __uint_as_float(tp[16] << 16);
            float p1 = u * __uint_as_float(tp[16] & 0xffff0000u);
            float p2 = u * __uint_as_float(tp[17] << 16);
            float p3 = u * __uint_as_float(tp[17] & 0xffff0000u);
            float p4 = u * __uint_as_float(tp[18] << 16);
            float p5 = u * __uint_as_float(tp[18] & 0xffff0000u);
            float p6 = u * __uint_as_float(tp[19] << 16);
            float p7 = u * __uint_as_float(tp[19] & 0xffff0000u);
            float q0 = mixv(p0, p1, b0, 1);
            float q1 = mixv(p2, p3, b0, 1);
            float q2 = mixv(p4, p5, b0, 1);
            float q3 = mixv(p6, p7, b0, 1);
            float r0 = mixv(q0, q1, b1, 2);
            float r1 = mixv(q2, q3, b1, 2);
            float t0 = mixv(r0, r1, b2, 4);
            t0 += __shfl_xor(t0, 8);
            fused_upd(j + (lane & 7), k, t0, !(lane & 8),
                      reci, recf, S4f, wi, last, writeWi);
        }
        if (rem & 4) {
            int j = beg + rbase + (rem & 8);
            float p0 = u * __uint_as_float(tp[20] << 16);
            float p1 = u * __uint_as_float(tp[20] & 0xffff0000u);
            float p2 = u * __uint_as_float(tp[21] << 16);
            float p3 = u * __uint_as_float(tp[21] & 0xffff0000u);
            float q0 = mixv(p0, p1, b0, 1);
            float q1 = mixv(p2, p3, b0, 1);
            float r0 = mixv(q0, q1, b1, 2);
            r0 += __shfl_xor(r0, 4);
            r0 += __shfl_xor(r0, 8);
            fused_upd(j + (lane & 3), k, r0, !(lane & 12),
                      reci, recf, S4f, wi, last, writeWi);
        }
    } else {
        for (int j = beg; j < end; j += 4) {
            int s0 = R_SRC(j + 0);
            int s1 = R_SRC(j + 1);
            int s2 = R_SRC(j + 2);
            int s3 = R_SRC(j + 3);
            float p0 = red16(u * cvt_hi(cmbI[s0 + lane]));
            float p1 = red16(u * cvt_hi(cmbI[s1 + lane]));
            float p2 = red16(u * cvt_hi(cmbI[s2 + lane]));
            float p3 = red16(u * cvt_hi(cmbI[s3 + lane]));
            int sl = lane & 3;
            float dv = p0;
            dv = (sl == 1) ? p1 : dv;
            dv = (sl == 2) ? p2 : dv;
            dv = (sl == 3) ? p3 : dv;
            fused_upd(j + sl, k, dv, !(lane & 12),
                      reci, recf, S4f, wi, last, writeWi);
        }
    }
}

extern "C" void kernel_launch(void* const* d_in, const int* in_sizes, int n_in,
                              void* d_out, int out_size, void* d_ws, size_t ws_size,
                              hipStream_t stream) {
    const float* user = (const float*)d_in[0];
    const float* item = (const float*)d_in[1];
    const float* S_in = (const float*)d_in[2];
    const int* edge = (const int*)d_in[3];
    const int* row0 = edge;
    const int* col0 = edge + NE;

    float* out = (float*)d_out;
    float* allemb = out;              // NN*DIM floats
    float* Sfinal = out + NN * DIM;   // KF*NE floats

    char* ws = (char*)d_ws;
    size_t off = 0;
    auto carve = [&](size_t bytes) { void* p = ws + off; off += (bytes + 255) & ~(size_t)255; return p; };
    int* ptr = (int*)carve((NN + 1) * sizeof(int));
    int* pos = (int*)carve((NN + 1) * sizeof(int));
    int* bsum = (int*)carve(256 * sizeof(int));
    int* offs = (int*)carve(256 * sizeof(int));
    int* srcadjI = (int*)carve((size_t)NSLOT_MAX * sizeof(int));
    int* jpos1 = (int*)carve((size_t)NE * sizeof(int));
    float* dinv = (float*)carve(NN * sizeof(float));
    float4* Scur4 = (float4*)carve((size_t)NEPU_MAX * sizeof(float4));
    // contiguous zero-region: cnt | rec8 | wi  (ONE bulk memset)
    size_t zbeg = off;
    int* cnt = (int*)carve((NN + 1) * sizeof(int));
    int4* rec4 = (int4*)carve((size_t)NEPU_MAX * 2 * sizeof(int4));   // 32B/slot
    float4* wi = (float4*)carve((size_t)NEPI_MAX * sizeof(float4));
    size_t zlen = off - zbeg;
    unsigned short* egoUA = (unsigned short*)carve((size_t)NUM_USER * DIM * 2);
    unsigned short* egoUB = (unsigned short*)carve((size_t)NUM_USER * DIM * 2);
    unsigned* cmbIA = (unsigned*)carve((size_t)NUM_ITEM * DIM * 4);
    unsigned* cmbIB = (unsigned*)carve((size_t)NUM_ITEM * DIM * 4);

    hipMemsetAsync(ws + zbeg, 0, zlen, stream);

    k_setup<<<NB_SETUP, 256, 0, stream>>>(user, item, egoUA, cmbIA, allemb,
                                          row0, col0, cnt);
    k_scan1<<<NBLK_SCAN, SCAN_CHUNK, 0, stream>>>(cnt, dinv, ptr, bsum);
    k_scan2<<<1, 256, 0, stream>>>(bsum, offs);
    k_scan3<<<(NN + 1 + 255) / 256, 256, 0, stream>>>(ptr, offs, pos, cnt, srcadjI);
    k_fillw0<<<(NE + 255) / 256, 256, 0, stream>>>(row0, col0, S_in, dinv, pos,
                                                   ptr, rec4, srcadjI, jpos1);

    unsigned short* egoU = egoUA;
    unsigned short* egoUn = egoUB;
    unsigned* cmbI = cmbIA;
    unsigned* cmbIn = cmbIB;
    for (int layer = 0; layer < 2; ++layer) {
        for (int it = 0; it < 2; ++it) {
            int flags = 0;
            if (it == 0) flags |= 8;                   // scatter wi (consumed at it=1)
            if (it == 1) flags |= 1;                   // layer end: allemb += acc
            if (it == 1 && layer == 0) flags |= 4;     // write next ego (+item T)
            int last = (layer == 1 && it == 1) ? 1 : 0;
            // non-layer-end: item x_new is never consumed -> user-only grid
            int nlim = (it == 1) ? NN : NUM_USER;
            k_conv_score<<<(nlim * 64 + 255) / 256, 256, 0, stream>>>(
                ptr, (const int*)rec4, (float*)rec4, srcadjI, (float*)wi,
                (float*)Scur4, egoU, cmbI, egoUn, cmbIn, allemb,
                flags, last, nlim);
        }
        unsigned short* t = egoU; egoU = egoUn; egoUn = t;
        unsigned* tc = cmbI; cmbI = cmbIn; cmbIn = tc;
    }
    k_sout<<<(NE + 255) / 256, 256, 0, stream>>>(Scur4, jpos1, Sfinal);
}

// Round 12
// 357.710 us; speedup vs baseline: 1.1054x; 1.0475x over previous
//
#include <hip/hip_runtime.h>

#define NUM_USER 60000
#define NUM_ITEM 40000
#define NN 100000
#define NE 500000
#define DIM 64
#define KF 4
#define SCAN_CHUNK 512
#define NBLK_SCAN ((NN + 1 + SCAN_CHUNK - 1) / SCAN_CHUNK)
// padded slot-count upper bounds (each node rounds up to multiple of 4)
#define NEPU_MAX (NE + 3 * NUM_USER)   // 680000 user-side slots max
#define NEPI_MAX (NE + 3 * NUM_ITEM)   // 620000 item-side slots max
#define NSLOT_MAX (NEPU_MAX + NEPI_MAX)
#define MAXU_SLOTS 44                  // register-cached user path handles <=44 slots
#define NB_U4 (NUM_USER * DIM / 4 / 256)   // 3750 user-init blocks (float4/thread)
#define NB_I (NUM_ITEM / 16)               // 2500 item-init blocks (16 nodes/block)
#define NB_SETUP (NB_U4 + NB_I)            // 6250
#define EPB (NE / NB_SETUP)                // 80 edges counted per setup block

// sum within each 16-lane group (butterfly: all lanes get result)
__device__ __forceinline__ float red16(float v) {
    v += __shfl_xor(v, 1);
    v += __shfl_xor(v, 2);
    v += __shfl_xor(v, 4);
    v += __shfl_xor(v, 8);
    return v;
}

__device__ __forceinline__ float b2f(unsigned short u) {
    return __uint_as_float(((unsigned)u) << 16);
}
__device__ __forceinline__ unsigned short f2b(float x) {
    unsigned u = __float_as_uint(x);
    u = (u + 0x7fffu + ((u >> 16) & 1u)) >> 16;   // RNE
    return (unsigned short)u;
}
// combined item word: high16 = T (bf16 bits), low16 = ego (bf16 bits)
__device__ __forceinline__ float cvt_lo(unsigned c) { return __uint_as_float(c << 16); }
__device__ __forceinline__ float cvt_hi(unsigned c) { return __uint_as_float(c & 0xffff0000u); }
// pack hi16 halves of two combined words: lo16(out)=hi16(c0), hi16(out)=hi16(c1)
__device__ __forceinline__ unsigned packhi(unsigned c0, unsigned c1) {
#if defined(__has_builtin) && __has_builtin(__builtin_amdgcn_perm)
    return __builtin_amdgcn_perm(c1, c0, 0x07060302u);
#else
    return (c0 >> 16) | (c1 & 0xffff0000u);
#endif
}
// mixed-butterfly level: lane keeps the value whose slot-bit matches its lane bit
__device__ __forceinline__ float mixv(float x, float y, bool b, int m) {
    return (b ? y : x) + __shfl_xor(b ? x : y, m);
}

__device__ __forceinline__ float4 softmax4(float4 s) {
    float m = fmaxf(fmaxf(s.x, s.y), fmaxf(s.z, s.w));
    float e0 = __expf(s.x - m), e1 = __expf(s.y - m);
    float e2 = __expf(s.z - m), e3 = __expf(s.w - m);
    float inv = 1.0f / (e0 + e1 + e2 + e3);
    return make_float4(e0 * inv, e1 * inv, e2 * inv, e3 * inv);
}

// Fused per-slot S/weight update (single weight buffer: every access to a
// user slot is by its owning lane, read-before-write in program order).
// nj = {jit, n, 1/n, 0} per slot (one 16B load). softmax(S_old) = w*(1/n).
// snew = w*rn + dot. last: S4f <- snew; else w' = n*softmax_k(snew) -> wu
// (+ wi item-order scatter only when writeWi; it=1's wi is never consumed).
__device__ __forceinline__ void fused_upd(int jj, int k, float dot, bool wr,
        float* __restrict__ wu, float* __restrict__ S4f,
        const int4* __restrict__ nj4, float* __restrict__ wiW,
        int last, int writeWi) {
    float w = wu[4 * jj + k];
    int4 nj = nj4[jj];
    float n = __int_as_float(nj.y);
    float rn = __int_as_float(nj.z);
    float snew = fmaf(w, rn, dot);
    if (last) {
        if (wr) S4f[4 * jj + k] = snew;
        return;
    }
    float m2 = fmaxf(snew, __shfl_xor(snew, 16));
    m2 = fmaxf(m2, __shfl_xor(m2, 32));
    float e2 = __expf(snew - m2);
    float s2 = e2 + __shfl_xor(e2, 16);
    s2 += __shfl_xor(s2, 32);
    if (wr && n > 0.0f) {
        float wn = n * e2 * (1.0f / s2);
        wu[4 * jj + k] = wn;
        if (writeWi) wiW[4 * nj.x + k] = wn;
    }
}

// init (vectorized 4 dims/thread) + DISTRIBUTED degree count (80 edges/block,
// threads 0..159 one endpoint each). The atomic RETURN VALUE is the edge's
// per-node rank -- stored (coalesced) so the fill pass needs NO atomics.
__global__ void k_setup(const float* __restrict__ user, const float* __restrict__ item,
                        unsigned short* __restrict__ egoU, unsigned* __restrict__ cmbI,
                        float* __restrict__ allemb, const int* __restrict__ row0,
                        const int* __restrict__ col0, int* __restrict__ cnt,
                        int* __restrict__ rankR, int* __restrict__ rankC) {
    int b = blockIdx.x, t = threadIdx.x;
    int ebase = b * EPB;
    if (t < EPB) rankR[ebase + t] = atomicAdd(&cnt[row0[ebase + t]], 1);
    else if (t < 2 * EPB) rankC[ebase + t - EPB] = atomicAdd(&cnt[col0[ebase + t - EPB]], 1);
    if (b < NB_U4) {
        // user: pure streaming copy, float4/thread
        int idx = (b * 256 + t) * 4;
        float4 v = *(const float4*)(user + idx);
        ushort4 e;
        e.x = f2b(v.x); e.y = f2b(v.y); e.z = f2b(v.z); e.w = f2b(v.w);
        *(ushort4*)(egoU + idx) = e;
        *(float4*)(allemb + idx) = v;
    } else {
        // item: 16 lanes/node, float4/lane; 16-dim norm = 4-lane reduce
        int bb = b - NB_U4;
        int lane = t & 63;
        int nodeI = bb * 16 + ((t >> 6) << 2) + (lane >> 4);
        int idx = nodeI * DIM + (lane & 15) * 4;
        float4 v = *(const float4*)(item + idx);
        float ss = v.x * v.x + v.y * v.y + v.z * v.z + v.w * v.w;
        ss += __shfl_xor(ss, 1);
        ss += __shfl_xor(ss, 2);
        float rinv = 1.0f / fmaxf(sqrtf(ss), 1e-12f);
        uint4 o;
        o.x = (((unsigned)f2b(tanhf(v.x * rinv))) << 16) | (unsigned)f2b(v.x);
        o.y = (((unsigned)f2b(tanhf(v.y * rinv))) << 16) | (unsigned)f2b(v.y);
        o.z = (((unsigned)f2b(tanhf(v.z * rinv))) << 16) | (unsigned)f2b(v.z);
        o.w = (((unsigned)f2b(tanhf(v.w * rinv))) << 16) | (unsigned)f2b(v.w);
        *(uint4*)(cmbI + idx) = o;
        *(float4*)(allemb + NUM_USER * DIM + idx) = v;
    }
}

// --- 3-stage exclusive scan over padded counts -> ptr[NN+1]; dinv fused ---
__global__ void k_scan1(const int* __restrict__ cnt, float* __restrict__ dinv,
                        int* __restrict__ ptr, int* __restrict__ bsum) {
    __shared__ int sm[SCAN_CHUNK];
    int tid = threadIdx.x;
    int idx = blockIdx.x * SCAN_CHUNK + tid;
    int d = (idx < NN) ? cnt[idx] : 0;
    if (idx < NN) dinv[idx] = (d > 0) ? rsqrtf((float)d) : 0.0f;
    int x = (d + 3) & ~3;
    sm[tid] = x;
    __syncthreads();
    for (int off = 1; off < SCAN_CHUNK; off <<= 1) {
        int v = (tid >= off) ? sm[tid - off] : 0;
        __syncthreads();
        sm[tid] += v;
        __syncthreads();
    }
    if (idx <= NN) ptr[idx] = sm[tid] - x;
    if (tid == SCAN_CHUNK - 1) bsum[blockIdx.x] = sm[tid];
}

__global__ void k_scan2(int* __restrict__ bsum, int* __restrict__ offs) {
    __shared__ int sm[256];
    int tid = threadIdx.x;
    int x = (tid < NBLK_SCAN) ? bsum[tid] : 0;
    sm[tid] = x;
    __syncthreads();
    for (int off = 1; off < 256; off <<= 1) {
        int v = (tid >= off) ? sm[tid - off] : 0;
        __syncthreads();
        sm[tid] += v;
        __syncthreads();
    }
    if (tid < NBLK_SCAN) offs[tid] = sm[tid] - x;
}

// finalize scan; zero dummy-slot srcadj (end computable locally from cnt)
__global__ void k_scan3(int* __restrict__ ptr, const int* __restrict__ offs,
                        const int* __restrict__ cnt, int* __restrict__ srcadj) {
    int idx = blockIdx.x * blockDim.x + threadIdx.x;
    if (idx > NN) return;
    int v = ptr[idx] + offs[idx / SCAN_CHUNK];
    ptr[idx] = v;
    if (idx < NN) {
        int d = cnt[idx];
        int end = v + ((d + 3) & ~3);
        for (int j = v + d; j < end; ++j) srcadj[j] = 0;
    }
}

// fill CSR + w0, ATOMIC-FREE: j1/j0 derived from the ranks captured in setup.
// Per edge: coalesced row/col/rank/Sin reads, L2-resident ptr/dinv gathers,
// fire-and-forget scatter of srcadj[j1], srcadj[j0], nj4[j1], wu[j1].
__global__ void k_fillw0(const int* __restrict__ row0, const int* __restrict__ col0,
                         const int* __restrict__ rankR, const int* __restrict__ rankC,
                         const float* __restrict__ Sin, const float* __restrict__ dinv,
                         const int* __restrict__ ptr, int* __restrict__ srcadj,
                         int4* __restrict__ nj4, float4* __restrict__ wu,
                         int* __restrict__ jpos1) {
    int e = blockIdx.x * blockDim.x + threadIdx.x;
    if (e >= NE) return;
    int r = row0[e], c = col0[e];
    int ptrU = ptr[NUM_USER];
    int j1 = ptr[r] + rankR[e];
    int j0 = ptr[c] + rankC[e];
    srcadj[j1] = (c - NUM_USER) << 6;
    srcadj[j0] = r << 6;
    jpos1[e] = j1;
    float n = dinv[r] * dinv[c];
    float4 s = make_float4(Sin[e], Sin[NE + e], Sin[2 * NE + e], Sin[3 * NE + e]);
    float4 p = softmax4(s);
    nj4[j1] = make_int4(j0 - ptrU, __float_as_int(n), __float_as_int(1.0f / n), 0);
    wu[j1] = make_float4(n * p.x, n * p.y, n * p.z, n * p.w);
}

// Scur4 (slot order, written by last conv) -> Sout [4][E] edge order
__global__ void k_sout(const float4* __restrict__ Scur4, const int* __restrict__ jpos1,
                       float* __restrict__ Sout) {
    int e = blockIdx.x * blockDim.x + threadIdx.x;
    if (e >= NE) return;
    float4 s = Scur4[jpos1[e]];
    Sout[e] = s.x;
    Sout[NE + e] = s.y;
    Sout[2 * NE + e] = s.z;
    Sout[3 * NE + e] = s.w;
}

// ---- user conv block macros: 16 outstanding gathers per issue point ----
// (srcadj values are pre-scaled by DIM)
#define UCONV16(JOFF, TP0) do { \
    int j = beg + (JOFF); \
    int4 sA = *(const int4*)(srcadj + j); \
    int4 sB = *(const int4*)(srcadj + j + 4); \
    int4 sC = *(const int4*)(srcadj + j + 8); \
    int4 sD = *(const int4*)(srcadj + j + 12); \
    unsigned c0 = cmbI[sA.x + lane]; \
    unsigned c1 = cmbI[sA.y + lane]; \
    unsigned c2 = cmbI[sA.z + lane]; \
    unsigned c3 = cmbI[sA.w + lane]; \
    unsigned c4 = cmbI[sB.x + lane]; \
    unsigned c5 = cmbI[sB.y + lane]; \
    unsigned c6 = cmbI[sB.z + lane]; \
    unsigned c7 = cmbI[sB.w + lane]; \
    unsigned c8 = cmbI[sC.x + lane]; \
    unsigned c9 = cmbI[sC.y + lane]; \
    unsigned c10 = cmbI[sC.z + lane]; \
    unsigned c11 = cmbI[sC.w + lane]; \
    unsigned c12 = cmbI[sD.x + lane]; \
    unsigned c13 = cmbI[sD.y + lane]; \
    unsigned c14 = cmbI[sD.z + lane]; \
    unsigned c15 = cmbI[sD.w + lane]; \
    a0 = fmaf(wu[4 * j + k], cvt_lo(c0), a0); \
    a1 = fmaf(wu[4 * j + 4 + k], cvt_lo(c1), a1); \
    a2 = fmaf(wu[4 * j + 8 + k], cvt_lo(c2), a2); \
    a3 = fmaf(wu[4 * j + 12 + k], cvt_lo(c3), a3); \
    a0 = fmaf(wu[4 * j + 16 + k], cvt_lo(c4), a0); \
    a1 = fmaf(wu[4 * j + 20 + k], cvt_lo(c5), a1); \
    a2 = fmaf(wu[4 * j + 24 + k], cvt_lo(c6), a2); \
    a3 = fmaf(wu[4 * j + 28 + k], cvt_lo(c7), a3); \
    a0 = fmaf(wu[4 * j + 32 + k], cvt_lo(c8), a0); \
    a1 = fmaf(wu[4 * j + 36 + k], cvt_lo(c9), a1); \
    a2 = fmaf(wu[4 * j + 40 + k], cvt_lo(c10), a2); \
    a3 = fmaf(wu[4 * j + 44 + k], cvt_lo(c11), a3); \
    a0 = fmaf(wu[4 * j + 48 + k], cvt_lo(c12), a0); \
    a1 = fmaf(wu[4 * j + 52 + k], cvt_lo(c13), a1); \
    a2 = fmaf(wu[4 * j + 56 + k], cvt_lo(c14), a2); \
    a3 = fmaf(wu[4 * j + 60 + k], cvt_lo(c15), a3); \
    tp[(TP0) + 0] = packhi(c0, c1); \
    tp[(TP0) + 1] = packhi(c2, c3); \
    tp[(TP0) + 2] = packhi(c4, c5); \
    tp[(TP0) + 3] = packhi(c6, c7); \
    tp[(TP0) + 4] = packhi(c8, c9); \
    tp[(TP0) + 5] = packhi(c10, c11); \
    tp[(TP0) + 6] = packhi(c12, c13); \
    tp[(TP0) + 7] = packhi(c14, c15); \
} while (0)

#define UCONV8(JOFF, TP0) do { \
    int j = beg + (JOFF); \
    int4 sA = *(const int4*)(srcadj + j); \
    int4 sB = *(const int4*)(srcadj + j + 4); \
    unsigned c0 = cmbI[sA.x + lane]; \
    unsigned c1 = cmbI[sA.y + lane]; \
    unsigned c2 = cmbI[sA.z + lane]; \
    unsigned c3 = cmbI[sA.w + lane]; \
    unsigned c4 = cmbI[sB.x + lane]; \
    unsigned c5 = cmbI[sB.y + lane]; \
    unsigned c6 = cmbI[sB.z + lane]; \
    unsigned c7 = cmbI[sB.w + lane]; \
    a0 = fmaf(wu[4 * j + k], cvt_lo(c0), a0); \
    a1 = fmaf(wu[4 * j + 4 + k], cvt_lo(c1), a1); \
    a2 = fmaf(wu[4 * j + 8 + k], cvt_lo(c2), a2); \
    a3 = fmaf(wu[4 * j + 12 + k], cvt_lo(c3), a3); \
    a0 = fmaf(wu[4 * j + 16 + k], cvt_lo(c4), a0); \
    a1 = fmaf(wu[4 * j + 20 + k], cvt_lo(c5), a1); \
    a2 = fmaf(wu[4 * j + 24 + k], cvt_lo(c6), a2); \
    a3 = fmaf(wu[4 * j + 28 + k], cvt_lo(c7), a3); \
    tp[(TP0) + 0] = packhi(c0, c1); \
    tp[(TP0) + 1] = packhi(c2, c3); \
    tp[(TP0) + 2] = packhi(c4, c5); \
    tp[(TP0) + 3] = packhi(c6, c7); \
} while (0)

#define UCONV4(JOFF, TP0) do { \
    int j = beg + (JOFF); \
    int4 sA = *(const int4*)(srcadj + j); \
    unsigned c0 = cmbI[sA.x + lane]; \
    unsigned c1 = cmbI[sA.y + lane]; \
    unsigned c2 = cmbI[sA.z + lane]; \
    unsigned c3 = cmbI[sA.w + lane]; \
    a0 = fmaf(wu[4 * j + k], cvt_lo(c0), a0); \
    a1 = fmaf(wu[4 * j + 4 + k], cvt_lo(c1), a1); \
    a2 = fmaf(wu[4 * j + 8 + k], cvt_lo(c2), a2); \
    a3 = fmaf(wu[4 * j + 12 + k], cvt_lo(c3), a3); \
    tp[(TP0) + 0] = packhi(c0, c1); \
    tp[(TP0) + 1] = packhi(c2, c3); \
} while (0)

// fused gather conv + routing score + S/weight update.
// wave per node; lane = dim, k = lane>>4 = factor.
// nlim: NUM_USER on non-layer-end dispatches (item conv output unused there),
// NN on layer-end. Single weight buffer each side; wi scattered when flags&8.
// flags: 1 = layer end (allemb += acc), 4 = write next ego (items: +tanh T),
// 8 = scatter wi.
__global__ __launch_bounds__(256, 4) void k_conv_score(
        const int* __restrict__ ptr, const int* __restrict__ srcadj,
        float* __restrict__ wu, float* __restrict__ wi,
        float* __restrict__ S4f, const int4* __restrict__ nj4,
        const unsigned short* __restrict__ egoU, const unsigned* __restrict__ cmbI,
        unsigned short* __restrict__ xnextU, unsigned* __restrict__ cmbNext,
        float* __restrict__ allemb, int flags, int last, int nlim) {
    int node = (blockIdx.x * blockDim.x + threadIdx.x) >> 6;
    int lane = threadIdx.x & 63;
    if (node >= nlim) return;
    int beg = __builtin_amdgcn_readfirstlane(ptr[node]);
    int end = __builtin_amdgcn_readfirstlane(ptr[node + 1]);
    int count = end - beg;
    int k = lane >> 4;
    int writeWi = flags & 8;

    float a0 = 0.0f, a1 = 0.0f, a2 = 0.0f, a3 = 0.0f;

    if (node >= NUM_USER) {
        // ---- item side: conv only, 16-deep (runs only on layer-end) ----
        int ptrU = __builtin_amdgcn_readfirstlane(ptr[NUM_USER]);
        const float* wT = wi + (size_t)4 * (beg - ptrU);
        int t = 0;
        for (; t + 16 <= count; t += 16) {
            int4 sA = *(const int4*)(srcadj + beg + t);
            int4 sB = *(const int4*)(srcadj + beg + t + 4);
            int4 sC = *(const int4*)(srcadj + beg + t + 8);
            int4 sD = *(const int4*)(srcadj + beg + t + 12);
            a0 = fmaf(wT[4 * t + k], b2f(egoU[sA.x + lane]), a0);
            a1 = fmaf(wT[4 * t + 4 + k], b2f(egoU[sA.y + lane]), a1);
            a2 = fmaf(wT[4 * t + 8 + k], b2f(egoU[sA.z + lane]), a2);
            a3 = fmaf(wT[4 * t + 12 + k], b2f(egoU[sA.w + lane]), a3);
            a0 = fmaf(wT[4 * t + 16 + k], b2f(egoU[sB.x + lane]), a0);
            a1 = fmaf(wT[4 * t + 20 + k], b2f(egoU[sB.y + lane]), a1);
            a2 = fmaf(wT[4 * t + 24 + k], b2f(egoU[sB.z + lane]), a2);
            a3 = fmaf(wT[4 * t + 28 + k], b2f(egoU[sB.w + lane]), a3);
            a0 = fmaf(wT[4 * t + 32 + k], b2f(egoU[sC.x + lane]), a0);
            a1 = fmaf(wT[4 * t + 36 + k], b2f(egoU[sC.y + lane]), a1);
            a2 = fmaf(wT[4 * t + 40 + k], b2f(egoU[sC.z + lane]), a2);
            a3 = fmaf(wT[4 * t + 44 + k], b2f(egoU[sC.w + lane]), a3);
            a0 = fmaf(wT[4 * t + 48 + k], b2f(egoU[sD.x + lane]), a0);
            a1 = fmaf(wT[4 * t + 52 + k], b2f(egoU[sD.y + lane]), a1);
            a2 = fmaf(wT[4 * t + 56 + k], b2f(egoU[sD.z + lane]), a2);
            a3 = fmaf(wT[4 * t + 60 + k], b2f(egoU[sD.w + lane]), a3);
        }
        if (count & 8) {
            int4 sA = *(const int4*)(srcadj + beg + t);
            int4 sB = *(const int4*)(srcadj + beg + t + 4);
            a0 = fmaf(wT[4 * t + k], b2f(egoU[sA.x + lane]), a0);
            a1 = fmaf(wT[4 * t + 4 + k], b2f(egoU[sA.y + lane]), a1);
            a2 = fmaf(wT[4 * t + 8 + k], b2f(egoU[sA.z + lane]), a2);
            a3 = fmaf(wT[4 * t + 12 + k], b2f(egoU[sA.w + lane]), a3);
            a0 = fmaf(wT[4 * t + 16 + k], b2f(egoU[sB.x + lane]), a0);
            a1 = fmaf(wT[4 * t + 20 + k], b2f(egoU[sB.y + lane]), a1);
            a2 = fmaf(wT[4 * t + 24 + k], b2f(egoU[sB.z + lane]), a2);
            a3 = fmaf(wT[4 * t + 28 + k], b2f(egoU[sB.w + lane]), a3);
            t += 8;
        }
        if (count & 4) {
            int4 sA = *(const int4*)(srcadj + beg + t);
            a0 = fmaf(wT[4 * t + k], b2f(egoU[sA.x + lane]), a0);
            a1 = fmaf(wT[4 * t + 4 + k], b2f(egoU[sA.y + lane]), a1);
            a2 = fmaf(wT[4 * t + 8 + k], b2f(egoU[sA.z + lane]), a2);
            a3 = fmaf(wT[4 * t + 12 + k], b2f(egoU[sA.w + lane]), a3);
        }
        float acc = (a0 + a1) + (a2 + a3);
        if (flags & 1) {
            int i = node * DIM + lane;
            allemb[i] += acc;
            if (flags & 4) {
                float ss = red16(acc * acc);
                float tt = tanhf(acc / fmaxf(sqrtf(ss), 1e-12f));
                cmbNext[i - NUM_USER * DIM] =
                    (((unsigned)f2b(tt)) << 16) | (unsigned)f2b(acc);
            }
        }
        return;
    }

    // ---- user side: conv + routing score + fused S/w update ----
    unsigned tp[22];          // packed T cache: 2 slots/word, static-indexed
    bool big = count > MAXU_SLOTS;   // wave-uniform fallback (statistically never)
    int rem = count & 15;
    int rbase = count & ~15;

    if (!big) {
        if (count >= 16) UCONV16(0, 0);
        if (count >= 32) UCONV16(16, 8);
        if (rem & 8) UCONV8(rbase, 16);
        if (rem & 4) UCONV4(rbase + (rem & 8), 20);
    } else {
        for (int j = beg; j < end; j += 4) {
            int4 s = *(const int4*)(srcadj + j);
            a0 = fmaf(wu[4 * j + k], cvt_lo(cmbI[s.x + lane]), a0);
            a1 = fmaf(wu[4 * j + 4 + k], cvt_lo(cmbI[s.y + lane]), a1);
            a2 = fmaf(wu[4 * j + 8 + k], cvt_lo(cmbI[s.z + lane]), a2);
            a3 = fmaf(wu[4 * j + 12 + k], cvt_lo(cmbI[s.w + lane]), a3);
        }
    }
    float acc = (a0 + a1) + (a2 + a3);

    if (flags & 1) {
        int i = node * DIM + lane;
        allemb[i] += acc;
        if (flags & 4) xnextU[i] = f2b(acc);
    }

    // routing score from register cache + fused per-slot S/weight update
    float ssu = red16(acc * acc);
    float u = acc / fmaxf(sqrtf(ssu), 1e-12f);
    bool b0 = lane & 1;
    bool b1 = lane & 2;
    bool b2 = lane & 4;
    bool b3 = lane & 8;

    if (!big) {
#define USC16(JOFF, TP0) do { \
        int j = beg + (JOFF); \
        float p0 = u * __uint_as_float(tp[(TP0) + 0] << 16); \
        float p1 = u * __uint_as_float(tp[(TP0) + 0] & 0xffff0000u); \
        float p2 = u * __uint_as_float(tp[(TP0) + 1] << 16); \
        float p3 = u * __uint_as_float(tp[(TP0) + 1] & 0xffff0000u); \
        float p4 = u * __uint_as_float(tp[(TP0) + 2] << 16); \
        float p5 = u * __uint_as_float(tp[(TP0) + 2] & 0xffff0000u); \
        float p6 = u * __uint_as_float(tp[(TP0) + 3] << 16); \
        float p7 = u * __uint_as_float(tp[(TP0) + 3] & 0xffff0000u); \
        float p8 = u * __uint_as_float(tp[(TP0) + 4] << 16); \
        float p9 = u * __uint_as_float(tp[(TP0) + 4] & 0xffff0000u); \
        float p10 = u * __uint_as_float(tp[(TP0) + 5] << 16); \
        float p11 = u * __uint_as_float(tp[(TP0) + 5] & 0xffff0000u); \
        float p12 = u * __uint_as_float(tp[(TP0) + 6] << 16); \
        float p13 = u * __uint_as_float(tp[(TP0) + 6] & 0xffff0000u); \
        float p14 = u * __uint_as_float(tp[(TP0) + 7] << 16); \
        float p15 = u * __uint_as_float(tp[(TP0) + 7] & 0xffff0000u); \
        float q0 = mixv(p0, p1, b0, 1); \
        float q1 = mixv(p2, p3, b0, 1); \
        float q2 = mixv(p4, p5, b0, 1); \
        float q3 = mixv(p6, p7, b0, 1); \
        float q4 = mixv(p8, p9, b0, 1); \
        float q5 = mixv(p10, p11, b0, 1); \
        float q6 = mixv(p12, p13, b0, 1); \
        float q7 = mixv(p14, p15, b0, 1); \
        float r0 = mixv(q0, q1, b1, 2); \
        float r1 = mixv(q2, q3, b1, 2); \
        float r2 = mixv(q4, q5, b1, 2); \
        float r3 = mixv(q6, q7, b1, 2); \
        float s0 = mixv(r0, r1, b2, 4); \
        float s1 = mixv(r2, r3, b2, 4); \
        float t0 = mixv(s0, s1, b3, 8); \
        fused_upd(j + (lane & 15), k, t0, true, \
                  wu, S4f, nj4, wi, last, writeWi); \
} while (0)
        if (count >= 16) USC16(0, 0);
        if (count >= 32) USC16(16, 8);
        if (rem & 8) {
            int j = beg + rbase;
            float p0 = u * __uint_as_float(tp[16] << 16);
            float p1 = u * __uint_as_float(tp[16] & 0xffff0000u);
            float p2 = u * __uint_as_float(tp[17] << 16);
            float p3 = u * __uint_as_float(tp[17] & 0xffff0000u);
            float p4 = u * __uint_as_float(tp[18] << 16);
            float p5 = u * __uint_as_float(tp[18] & 0xffff0000u);
            float p6 = u * __uint_as_float(tp[19] << 16);
            float p7 = u * __uint_as_float(tp[19] & 0xffff0000u);
            float q0 = mixv(p0, p1, b0, 1);
            float q1 = mixv(p2, p3, b0, 1);
            float q2 = mixv(p4, p5, b0, 1);
            float q3 = mixv(p6, p7, b0, 1);
            float r0 = mixv(q0, q1, b1, 2);
            float r1 = mixv(q2, q3, b1, 2);
            float t0 = mixv(r0, r1, b2, 4);
            t0 += __shfl_xor(t0, 8);
            fused_upd(j + (lane & 7), k, t0, !(lane & 8),
                      wu, S4f, nj4, wi, last, writeWi);
        }
        if (rem & 4) {
            int j = beg + rbase + (rem & 8);
            float p0 = u * __uint_as_float(tp[20] << 16);
            float p1 = u * __uint_as_float(tp[20] & 0xffff0000u);
            float p2 = u * __uint_as_float(tp[21] << 16);
            float p3 = u * __uint_as_float(tp[21] & 0xffff0000u);
            float q0 = mixv(p0, p1, b0, 1);
            float q1 = mixv(p2, p3, b0, 1);
            float r0 = mixv(q0, q1, b1, 2);
            r0 += __shfl_xor(r0, 4);
            r0 += __shfl_xor(r0, 8);
            fused_upd(j + (lane & 3), k, r0, !(lane & 12),
                      wu, S4f, nj4, wi, last, writeWi);
        }
    } else {
        for (int j = beg; j < end; j += 4) {
            int4 s = *(const int4*)(srcadj + j);
            float p0 = red16(u * cvt_hi(cmbI[s.x + lane]));
            float p1 = red16(u * cvt_hi(cmbI[s.y + lane]));
            float p2 = red16(u * cvt_hi(cmbI[s.z + lane]));
            float p3 = red16(u * cvt_hi(cmbI[s.w + lane]));
            int sl = lane & 3;
            float dv = p0;
            dv = (sl == 1) ? p1 : dv;
            dv = (sl == 2) ? p2 : dv;
            dv = (sl == 3) ? p3 : dv;
            fused_upd(j + sl, k, dv, !(lane & 12),
                      wu, S4f, nj4, wi, last, writeWi);
        }
    }
}

extern "C" void kernel_launch(void* const* d_in, const int* in_sizes, int n_in,
                              void* d_out, int out_size, void* d_ws, size_t ws_size,
                              hipStream_t stream) {
    const float* user = (const float*)d_in[0];
    const float* item = (const float*)d_in[1];
    const float* S_in = (const float*)d_in[2];
    const int* edge = (const int*)d_in[3];
    const int* row0 = edge;
    const int* col0 = edge + NE;

    float* out = (float*)d_out;
    float* allemb = out;              // NN*DIM floats
    float* Sfinal = out + NN * DIM;   // KF*NE floats

    char* ws = (char*)d_ws;
    size_t off = 0;
    auto carve = [&](size_t bytes) { void* p = ws + off; off += (bytes + 255) & ~(size_t)255; return p; };
    int* ptr = (int*)carve((NN + 1) * sizeof(int));
    int* bsum = (int*)carve(256 * sizeof(int));
    int* offs = (int*)carve(256 * sizeof(int));
    int* srcadj = (int*)carve((size_t)NSLOT_MAX * sizeof(int));
    int* rankR = (int*)carve((size_t)NE * sizeof(int));
    int* rankC = (int*)carve((size_t)NE * sizeof(int));
    int* jpos1 = (int*)carve((size_t)NE * sizeof(int));
    float* dinv = (float*)carve(NN * sizeof(float));
    float4* Scur4 = (float4*)carve((size_t)NEPU_MAX * sizeof(float4));
    // contiguous zero-region: cnt | nj4 | wu | wi  (ONE bulk memset)
    size_t zbeg = off;
    int* cnt = (int*)carve((NN + 1) * sizeof(int));
    int4* nj4 = (int4*)carve((size_t)NEPU_MAX * sizeof(int4));
    float4* wu = (float4*)carve((size_t)NEPU_MAX * sizeof(float4));
    float4* wi = (float4*)carve((size_t)NEPI_MAX * sizeof(float4));
    size_t zlen = off - zbeg;
    unsigned short* egoUA = (unsigned short*)carve((size_t)NUM_USER * DIM * 2);
    unsigned short* egoUB = (unsigned short*)carve((size_t)NUM_USER * DIM * 2);
    unsigned* cmbIA = (unsigned*)carve((size_t)NUM_ITEM * DIM * 4);
    unsigned* cmbIB = (unsigned*)carve((size_t)NUM_ITEM * DIM * 4);

    hipMemsetAsync(ws + zbeg, 0, zlen, stream);

    k_setup<<<NB_SETUP, 256, 0, stream>>>(user, item, egoUA, cmbIA, allemb,
                                          row0, col0, cnt, rankR, rankC);
    k_scan1<<<NBLK_SCAN, SCAN_CHUNK, 0, stream>>>(cnt, dinv, ptr, bsum);
    k_scan2<<<1, 256, 0, stream>>>(bsum, offs);
    k_scan3<<<(NN + 1 + 255) / 256, 256, 0, stream>>>(ptr, offs, cnt, srcadj);
    k_fillw0<<<(NE + 255) / 256, 256, 0, stream>>>(row0, col0, rankR, rankC,
                                                   S_in, dinv, ptr, srcadj,
                                                   nj4, wu, jpos1);

    unsigned short* egoU = egoUA;
    unsigned short* egoUn = egoUB;
    unsigned* cmbI = cmbIA;
    unsigned* cmbIn = cmbIB;
    for (int layer = 0; layer < 2; ++layer) {
        for (int it = 0; it < 2; ++it) {
            int flags = 0;
            if (it == 0) flags |= 8;                   // scatter wi (consumed at it=1)
            if (it == 1) flags |= 1;                   // layer end: allemb += acc
            if (it == 1 && layer == 0) flags |= 4;     // write next ego (+item T)
            int last = (layer == 1 && it == 1) ? 1 : 0;
            // non-layer-end: item x_new is never consumed -> user-only grid
            int nlim = (it == 1) ? NN : NUM_USER;
            k_conv_score<<<(nlim * 64 + 255) / 256, 256, 0, stream>>>(
                ptr, srcadj, (float*)wu, (float*)wi, (float*)Scur4, nj4,
                egoU, cmbI, egoUn, cmbIn, allemb, flags, last, nlim);
        }
        unsigned short* t = egoU; egoU = egoUn; egoUn = t;
        unsigned* tc = cmbI; cmbI = cmbIn; cmbIn = tc;
    }
    k_sout<<<(NE + 255) / 256, 256, 0, stream>>>(Scur4, jpos1, Sfinal);
}

// Round 13
// 354.384 us; speedup vs baseline: 1.1158x; 1.0094x over previous
//
#include <hip/hip_runtime.h>

#define NUM_USER 60000
#define NUM_ITEM 40000
#define NN 100000
#define NE 500000
#define DIM 64
#define KF 4
#define SCAN_CHUNK 512
#define NBLK_SCAN ((NN + 1 + SCAN_CHUNK - 1) / SCAN_CHUNK)
// padded slot-count upper bounds (each node rounds up to multiple of 4)
#define NEPU_MAX (NE + 3 * NUM_USER)   // 680000 user-side slots max
#define NEPI_MAX (NE + 3 * NUM_ITEM)   // 620000 item-side slots max
#define NSLOT_MAX (NEPU_MAX + NEPI_MAX)
#define MAXU_SLOTS 44                  // register-cached user path handles <=44 slots
#define NB_U4 (NUM_USER * DIM / 4 / 256)   // 3750 user-init blocks (float4/thread)
#define NB_I (NUM_ITEM / 16)               // 2500 item-init blocks (16 nodes/block)
#define NB_SETUP (NB_U4 + NB_I)            // 6250
#define EPB (NE / NB_SETUP)                // 80 edges counted per setup block

// sum within each 16-lane group (butterfly: all lanes get result)
__device__ __forceinline__ float red16(float v) {
    v += __shfl_xor(v, 1);
    v += __shfl_xor(v, 2);
    v += __shfl_xor(v, 4);
    v += __shfl_xor(v, 8);
    return v;
}

__device__ __forceinline__ float b2f(unsigned short u) {
    return __uint_as_float(((unsigned)u) << 16);
}
__device__ __forceinline__ unsigned short f2b(float x) {
    unsigned u = __float_as_uint(x);
    u = (u + 0x7fffu + ((u >> 16) & 1u)) >> 16;   // RNE
    return (unsigned short)u;
}
// combined item word: high16 = T (bf16 bits), low16 = ego (bf16 bits)
__device__ __forceinline__ float cvt_lo(unsigned c) { return __uint_as_float(c << 16); }
__device__ __forceinline__ float cvt_hi(unsigned c) { return __uint_as_float(c & 0xffff0000u); }
// pack hi16 halves of two combined words: lo16(out)=hi16(c0), hi16(out)=hi16(c1)
__device__ __forceinline__ unsigned packhi(unsigned c0, unsigned c1) {
#if defined(__has_builtin) && __has_builtin(__builtin_amdgcn_perm)
    return __builtin_amdgcn_perm(c1, c0, 0x07060302u);
#else
    return (c0 >> 16) | (c1 & 0xffff0000u);
#endif
}
// mixed-butterfly level: lane keeps the value whose slot-bit matches its lane bit
__device__ __forceinline__ float mixv(float x, float y, bool b, int m) {
    return (b ? y : x) + __shfl_xor(b ? x : y, m);
}

__device__ __forceinline__ float4 softmax4(float4 s) {
    float m = fmaxf(fmaxf(s.x, s.y), fmaxf(s.z, s.w));
    float e0 = __expf(s.x - m), e1 = __expf(s.y - m);
    float e2 = __expf(s.z - m), e3 = __expf(s.w - m);
    float inv = 1.0f / (e0 + e1 + e2 + e3);
    return make_float4(e0 * inv, e1 * inv, e2 * inv, e3 * inv);
}

// Per-user-slot 32B record (ONE cache line): rec4[2j]={jit, n, 1/n, 0},
// rec4[2j+1]={w0,w1,w2,w3}. Dummy slots all-zero from bulk memset
// (n=0 -> update skipped; w=0 -> conv contribution zero).
#define RW(j, k) recf[8 * (j) + 4 + (k)]

// Fused per-slot S/weight update (single record: every access to a user slot
// is by its owning lane, read-before-write in program order).
// softmax(S_old) reconstructed as w*(1/n). snew = w*rn + dot.
// last: S4f <- snew (final output); else w' = n*softmax_k(snew) -> record
// (+ wi item-order scatter only when writeWi; it=1's wi is never consumed).
__device__ __forceinline__ void fused_upd(int jj, int k, float dot, bool wr,
        int4* __restrict__ rec4, float* __restrict__ S4f,
        float* __restrict__ wiW, int last, int writeWi) {
    float* recf = (float*)rec4;
    float w = RW(jj, k);
    int4 h = rec4[2 * jj];
    float n = __int_as_float(h.y);
    float rn = __int_as_float(h.z);
    float snew = fmaf(w, rn, dot);
    if (last) {
        if (wr) S4f[4 * jj + k] = snew;
        return;
    }
    float m2 = fmaxf(snew, __shfl_xor(snew, 16));
    m2 = fmaxf(m2, __shfl_xor(m2, 32));
    float e2 = __expf(snew - m2);
    float s2 = e2 + __shfl_xor(e2, 16);
    s2 += __shfl_xor(s2, 32);
    if (wr && n > 0.0f) {
        float wn = n * e2 * (1.0f / s2);
        RW(jj, k) = wn;
        if (writeWi) wiW[4 * h.x + k] = wn;
    }
}

// init (vectorized 4 dims/thread) + DISTRIBUTED degree count (80 edges/block,
// threads 0..159 one endpoint each). The atomic RETURN VALUE is the edge's
// per-node rank -- stored (coalesced) so the fill pass needs NO atomics.
__global__ void k_setup(const float* __restrict__ user, const float* __restrict__ item,
                        unsigned short* __restrict__ egoU, unsigned* __restrict__ cmbI,
                        float* __restrict__ allemb, const int* __restrict__ row0,
                        const int* __restrict__ col0, int* __restrict__ cnt,
                        int* __restrict__ rankR, int* __restrict__ rankC) {
    int b = blockIdx.x, t = threadIdx.x;
    int ebase = b * EPB;
    if (t < EPB) rankR[ebase + t] = atomicAdd(&cnt[row0[ebase + t]], 1);
    else if (t < 2 * EPB) rankC[ebase + t - EPB] = atomicAdd(&cnt[col0[ebase + t - EPB]], 1);
    if (b < NB_U4) {
        // user: pure streaming copy, float4/thread
        int idx = (b * 256 + t) * 4;
        float4 v = *(const float4*)(user + idx);
        ushort4 e;
        e.x = f2b(v.x); e.y = f2b(v.y); e.z = f2b(v.z); e.w = f2b(v.w);
        *(ushort4*)(egoU + idx) = e;
        *(float4*)(allemb + idx) = v;
    } else {
        // item: 16 lanes/node, float4/lane; 16-dim norm = 4-lane reduce
        int bb = b - NB_U4;
        int lane = t & 63;
        int nodeI = bb * 16 + ((t >> 6) << 2) + (lane >> 4);
        int idx = nodeI * DIM + (lane & 15) * 4;
        float4 v = *(const float4*)(item + idx);
        float ss = v.x * v.x + v.y * v.y + v.z * v.z + v.w * v.w;
        ss += __shfl_xor(ss, 1);
        ss += __shfl_xor(ss, 2);
        float rinv = 1.0f / fmaxf(sqrtf(ss), 1e-12f);
        uint4 o;
        o.x = (((unsigned)f2b(tanhf(v.x * rinv))) << 16) | (unsigned)f2b(v.x);
        o.y = (((unsigned)f2b(tanhf(v.y * rinv))) << 16) | (unsigned)f2b(v.y);
        o.z = (((unsigned)f2b(tanhf(v.z * rinv))) << 16) | (unsigned)f2b(v.z);
        o.w = (((unsigned)f2b(tanhf(v.w * rinv))) << 16) | (unsigned)f2b(v.w);
        *(uint4*)(cmbI + idx) = o;
        *(float4*)(allemb + NUM_USER * DIM + idx) = v;
    }
}

// --- 3-stage exclusive scan over padded counts -> ptr[NN+1]; dinv fused ---
__global__ void k_scan1(const int* __restrict__ cnt, float* __restrict__ dinv,
                        int* __restrict__ ptr, int* __restrict__ bsum) {
    __shared__ int sm[SCAN_CHUNK];
    int tid = threadIdx.x;
    int idx = blockIdx.x * SCAN_CHUNK + tid;
    int d = (idx < NN) ? cnt[idx] : 0;
    if (idx < NN) dinv[idx] = (d > 0) ? rsqrtf((float)d) : 0.0f;
    int x = (d + 3) & ~3;
    sm[tid] = x;
    __syncthreads();
    for (int off = 1; off < SCAN_CHUNK; off <<= 1) {
        int v = (tid >= off) ? sm[tid - off] : 0;
        __syncthreads();
        sm[tid] += v;
        __syncthreads();
    }
    if (idx <= NN) ptr[idx] = sm[tid] - x;
    if (tid == SCAN_CHUNK - 1) bsum[blockIdx.x] = sm[tid];
}

__global__ void k_scan2(int* __restrict__ bsum, int* __restrict__ offs) {
    __shared__ int sm[256];
    int tid = threadIdx.x;
    int x = (tid < NBLK_SCAN) ? bsum[tid] : 0;
    sm[tid] = x;
    __syncthreads();
    for (int off = 1; off < 256; off <<= 1) {
        int v = (tid >= off) ? sm[tid - off] : 0;
        __syncthreads();
        sm[tid] += v;
        __syncthreads();
    }
    if (tid < NBLK_SCAN) offs[tid] = sm[tid] - x;
}

// finalize scan; zero dummy-slot srcadj (end computable locally from cnt)
__global__ void k_scan3(int* __restrict__ ptr, const int* __restrict__ offs,
                        const int* __restrict__ cnt, int* __restrict__ srcadj) {
    int idx = blockIdx.x * blockDim.x + threadIdx.x;
    if (idx > NN) return;
    int v = ptr[idx] + offs[idx / SCAN_CHUNK];
    ptr[idx] = v;
    if (idx < NN) {
        int d = cnt[idx];
        int end = v + ((d + 3) & ~3);
        for (int j = v + d; j < end; ++j) srcadj[j] = 0;
    }
}

// fill CSR + w0, ATOMIC-FREE: j1/j0 derived from the ranks captured in setup.
// Per edge: coalesced row/col/rank/Sin reads, L2-resident ptr/dinv gathers,
// 3 scattered lines: srcadj[j1], srcadj[j0], rec[j1] (32B, one line).
__global__ void k_fillw0(const int* __restrict__ row0, const int* __restrict__ col0,
                         const int* __restrict__ rankR, const int* __restrict__ rankC,
                         const float* __restrict__ Sin, const float* __restrict__ dinv,
                         const int* __restrict__ ptr, int* __restrict__ srcadj,
                         int4* __restrict__ rec4, int* __restrict__ jpos1) {
    int e = blockIdx.x * blockDim.x + threadIdx.x;
    if (e >= NE) return;
    int r = row0[e], c = col0[e];
    int ptrU = ptr[NUM_USER];
    int j1 = ptr[r] + rankR[e];
    int j0 = ptr[c] + rankC[e];
    srcadj[j1] = (c - NUM_USER) << 6;
    srcadj[j0] = r << 6;
    jpos1[e] = j1;
    float n = dinv[r] * dinv[c];
    float4 s = make_float4(Sin[e], Sin[NE + e], Sin[2 * NE + e], Sin[3 * NE + e]);
    float4 p = softmax4(s);
    rec4[2 * j1] = make_int4(j0 - ptrU, __float_as_int(n),
                             __float_as_int(1.0f / n), 0);
    rec4[2 * j1 + 1] = make_int4(__float_as_int(n * p.x), __float_as_int(n * p.y),
                                 __float_as_int(n * p.z), __float_as_int(n * p.w));
    // both stores hit the same 32B-aligned region -> one dirty line
}

// Scur4 (slot order, written by last conv) -> Sout [4][E] edge order
__global__ void k_sout(const float4* __restrict__ Scur4, const int* __restrict__ jpos1,
                       float* __restrict__ Sout) {
    int e = blockIdx.x * blockDim.x + threadIdx.x;
    if (e >= NE) return;
    float4 s = Scur4[jpos1[e]];
    Sout[e] = s.x;
    Sout[NE + e] = s.y;
    Sout[2 * NE + e] = s.z;
    Sout[3 * NE + e] = s.w;
}

// ---- user conv block macros: 16 outstanding gathers per issue point ----
// (srcadj values pre-scaled by DIM; weights from the slot record stream)
#define UCONV16(JOFF, TP0) do { \
    int j = beg + (JOFF); \
    int4 sA = *(const int4*)(srcadj + j); \
    int4 sB = *(const int4*)(srcadj + j + 4); \
    int4 sC = *(const int4*)(srcadj + j + 8); \
    int4 sD = *(const int4*)(srcadj + j + 12); \
    unsigned c0 = cmbI[sA.x + lane]; \
    unsigned c1 = cmbI[sA.y + lane]; \
    unsigned c2 = cmbI[sA.z + lane]; \
    unsigned c3 = cmbI[sA.w + lane]; \
    unsigned c4 = cmbI[sB.x + lane]; \
    unsigned c5 = cmbI[sB.y + lane]; \
    unsigned c6 = cmbI[sB.z + lane]; \
    unsigned c7 = cmbI[sB.w + lane]; \
    unsigned c8 = cmbI[sC.x + lane]; \
    unsigned c9 = cmbI[sC.y + lane]; \
    unsigned c10 = cmbI[sC.z + lane]; \
    unsigned c11 = cmbI[sC.w + lane]; \
    unsigned c12 = cmbI[sD.x + lane]; \
    unsigned c13 = cmbI[sD.y + lane]; \
    unsigned c14 = cmbI[sD.z + lane]; \
    unsigned c15 = cmbI[sD.w + lane]; \
    a0 = fmaf(RW(j + 0, k), cvt_lo(c0), a0); \
    a1 = fmaf(RW(j + 1, k), cvt_lo(c1), a1); \
    a2 = fmaf(RW(j + 2, k), cvt_lo(c2), a2); \
    a3 = fmaf(RW(j + 3, k), cvt_lo(c3), a3); \
    a0 = fmaf(RW(j + 4, k), cvt_lo(c4), a0); \
    a1 = fmaf(RW(j + 5, k), cvt_lo(c5), a1); \
    a2 = fmaf(RW(j + 6, k), cvt_lo(c6), a2); \
    a3 = fmaf(RW(j + 7, k), cvt_lo(c7), a3); \
    a0 = fmaf(RW(j + 8, k), cvt_lo(c8), a0); \
    a1 = fmaf(RW(j + 9, k), cvt_lo(c9), a1); \
    a2 = fmaf(RW(j + 10, k), cvt_lo(c10), a2); \
    a3 = fmaf(RW(j + 11, k), cvt_lo(c11), a3); \
    a0 = fmaf(RW(j + 12, k), cvt_lo(c12), a0); \
    a1 = fmaf(RW(j + 13, k), cvt_lo(c13), a1); \
    a2 = fmaf(RW(j + 14, k), cvt_lo(c14), a2); \
    a3 = fmaf(RW(j + 15, k), cvt_lo(c15), a3); \
    tp[(TP0) + 0] = packhi(c0, c1); \
    tp[(TP0) + 1] = packhi(c2, c3); \
    tp[(TP0) + 2] = packhi(c4, c5); \
    tp[(TP0) + 3] = packhi(c6, c7); \
    tp[(TP0) + 4] = packhi(c8, c9); \
    tp[(TP0) + 5] = packhi(c10, c11); \
    tp[(TP0) + 6] = packhi(c12, c13); \
    tp[(TP0) + 7] = packhi(c14, c15); \
} while (0)

#define UCONV8(JOFF, TP0) do { \
    int j = beg + (JOFF); \
    int4 sA = *(const int4*)(srcadj + j); \
    int4 sB = *(const int4*)(srcadj + j + 4); \
    unsigned c0 = cmbI[sA.x + lane]; \
    unsigned c1 = cmbI[sA.y + lane]; \
    unsigned c2 = cmbI[sA.z + lane]; \
    unsigned c3 = cmbI[sA.w + lane]; \
    unsigned c4 = cmbI[sB.x + lane]; \
    unsigned c5 = cmbI[sB.y + lane]; \
    unsigned c6 = cmbI[sB.z + lane]; \
    unsigned c7 = cmbI[sB.w + lane]; \
    a0 = fmaf(RW(j + 0, k), cvt_lo(c0), a0); \
    a1 = fmaf(RW(j + 1, k), cvt_lo(c1), a1); \
    a2 = fmaf(RW(j + 2, k), cvt_lo(c2), a2); \
    a3 = fmaf(RW(j + 3, k), cvt_lo(c3), a3); \
    a0 = fmaf(RW(j + 4, k), cvt_lo(c4), a0); \
    a1 = fmaf(RW(j + 5, k), cvt_lo(c5), a1); \
    a2 = fmaf(RW(j + 6, k), cvt_lo(c6), a2); \
    a3 = fmaf(RW(j + 7, k), cvt_lo(c7), a3); \
    tp[(TP0) + 0] = packhi(c0, c1); \
    tp[(TP0) + 1] = packhi(c2, c3); \
    tp[(TP0) + 2] = packhi(c4, c5); \
    tp[(TP0) + 3] = packhi(c6, c7); \
} while (0)

#define UCONV4(JOFF, TP0) do { \
    int j = beg + (JOFF); \
    int4 sA = *(const int4*)(srcadj + j); \
    unsigned c0 = cmbI[sA.x + lane]; \
    unsigned c1 = cmbI[sA.y + lane]; \
    unsigned c2 = cmbI[sA.z + lane]; \
    unsigned c3 = cmbI[sA.w + lane]; \
    a0 = fmaf(RW(j + 0, k), cvt_lo(c0), a0); \
    a1 = fmaf(RW(j + 1, k), cvt_lo(c1), a1); \
    a2 = fmaf(RW(j + 2, k), cvt_lo(c2), a2); \
    a3 = fmaf(RW(j + 3, k), cvt_lo(c3), a3); \
    tp[(TP0) + 0] = packhi(c0, c1); \
    tp[(TP0) + 1] = packhi(c2, c3); \
} while (0)

// fused gather conv + routing score + S/weight update.
// wave per node; lane = dim, k = lane>>4 = factor.
// nlim: NUM_USER on non-layer-end dispatches (item conv output unused there),
// NN on layer-end. Per-user-slot 32B record {jit,n,1/n,w[4]}; wi scattered
// only when flags&8 (it=0 dispatches).
// flags: 1 = layer end (allemb += acc), 4 = write next ego (items: +tanh T),
// 8 = scatter wi.
__global__ __launch_bounds__(256, 4) void k_conv_score(
        const int* __restrict__ ptr, const int* __restrict__ srcadj,
        int4* __restrict__ rec4, float* __restrict__ wi,
        float* __restrict__ S4f, const unsigned short* __restrict__ egoU,
        const unsigned* __restrict__ cmbI, unsigned short* __restrict__ xnextU,
        unsigned* __restrict__ cmbNext, float* __restrict__ allemb,
        int flags, int last, int nlim) {
    int node = (blockIdx.x * blockDim.x + threadIdx.x) >> 6;
    int lane = threadIdx.x & 63;
    if (node >= nlim) return;
    int beg = __builtin_amdgcn_readfirstlane(ptr[node]);
    int end = __builtin_amdgcn_readfirstlane(ptr[node + 1]);
    int count = end - beg;
    int k = lane >> 4;
    int writeWi = flags & 8;
    float* recf = (float*)rec4;

    float a0 = 0.0f, a1 = 0.0f, a2 = 0.0f, a3 = 0.0f;

    if (node >= NUM_USER) {
        // ---- item side: conv only, 16-deep (runs only on layer-end) ----
        int ptrU = __builtin_amdgcn_readfirstlane(ptr[NUM_USER]);
        const float* wT = wi + (size_t)4 * (beg - ptrU);
        int t = 0;
        for (; t + 16 <= count; t += 16) {
            int4 sA = *(const int4*)(srcadj + beg + t);
            int4 sB = *(const int4*)(srcadj + beg + t + 4);
            int4 sC = *(const int4*)(srcadj + beg + t + 8);
            int4 sD = *(const int4*)(srcadj + beg + t + 12);
            a0 = fmaf(wT[4 * t + k], b2f(egoU[sA.x + lane]), a0);
            a1 = fmaf(wT[4 * t + 4 + k], b2f(egoU[sA.y + lane]), a1);
            a2 = fmaf(wT[4 * t + 8 + k], b2f(egoU[sA.z + lane]), a2);
            a3 = fmaf(wT[4 * t + 12 + k], b2f(egoU[sA.w + lane]), a3);
            a0 = fmaf(wT[4 * t + 16 + k], b2f(egoU[sB.x + lane]), a0);
            a1 = fmaf(wT[4 * t + 20 + k], b2f(egoU[sB.y + lane]), a1);
            a2 = fmaf(wT[4 * t + 24 + k], b2f(egoU[sB.z + lane]), a2);
            a3 = fmaf(wT[4 * t + 28 + k], b2f(egoU[sB.w + lane]), a3);
            a0 = fmaf(wT[4 * t + 32 + k], b2f(egoU[sC.x + lane]), a0);
            a1 = fmaf(wT[4 * t + 36 + k], b2f(egoU[sC.y + lane]), a1);
            a2 = fmaf(wT[4 * t + 40 + k], b2f(egoU[sC.z + lane]), a2);
            a3 = fmaf(wT[4 * t + 44 + k], b2f(egoU[sC.w + lane]), a3);
            a0 = fmaf(wT[4 * t + 48 + k], b2f(egoU[sD.x + lane]), a0);
            a1 = fmaf(wT[4 * t + 52 + k], b2f(egoU[sD.y + lane]), a1);
            a2 = fmaf(wT[4 * t + 56 + k], b2f(egoU[sD.z + lane]), a2);
            a3 = fmaf(wT[4 * t + 60 + k], b2f(egoU[sD.w + lane]), a3);
        }
        if (count & 8) {
            int4 sA = *(const int4*)(srcadj + beg + t);
            int4 sB = *(const int4*)(srcadj + beg + t + 4);
            a0 = fmaf(wT[4 * t + k], b2f(egoU[sA.x + lane]), a0);
            a1 = fmaf(wT[4 * t + 4 + k], b2f(egoU[sA.y + lane]), a1);
            a2 = fmaf(wT[4 * t + 8 + k], b2f(egoU[sA.z + lane]), a2);
            a3 = fmaf(wT[4 * t + 12 + k], b2f(egoU[sA.w + lane]), a3);
            a0 = fmaf(wT[4 * t + 16 + k], b2f(egoU[sB.x + lane]), a0);
            a1 = fmaf(wT[4 * t + 20 + k], b2f(egoU[sB.y + lane]), a1);
            a2 = fmaf(wT[4 * t + 24 + k], b2f(egoU[sB.z + lane]), a2);
            a3 = fmaf(wT[4 * t + 28 + k], b2f(egoU[sB.w + lane]), a3);
            t += 8;
        }
        if (count & 4) {
            int4 sA = *(const int4*)(srcadj + beg + t);
            a0 = fmaf(wT[4 * t + k], b2f(egoU[sA.x + lane]), a0);
            a1 = fmaf(wT[4 * t + 4 + k], b2f(egoU[sA.y + lane]), a1);
            a2 = fmaf(wT[4 * t + 8 + k], b2f(egoU[sA.z + lane]), a2);
            a3 = fmaf(wT[4 * t + 12 + k], b2f(egoU[sA.w + lane]), a3);
        }
        float acc = (a0 + a1) + (a2 + a3);
        if (flags & 1) {
            int i = node * DIM + lane;
            allemb[i] += acc;
            if (flags & 4) {
                float ss = red16(acc * acc);
                float tt = tanhf(acc / fmaxf(sqrtf(ss), 1e-12f));
                cmbNext[i - NUM_USER * DIM] =
                    (((unsigned)f2b(tt)) << 16) | (unsigned)f2b(acc);
            }
        }
        return;
    }

    // ---- user side: conv + routing score + fused S/w update ----
    unsigned tp[22];          // packed T cache: 2 slots/word, static-indexed
    bool big = count > MAXU_SLOTS;   // wave-uniform fallback (statistically never)
    int rem = count & 15;
    int rbase = count & ~15;

    if (!big) {
        if (count >= 16) UCONV16(0, 0);
        if (count >= 32) UCONV16(16, 8);
        if (rem & 8) UCONV8(rbase, 16);
        if (rem & 4) UCONV4(rbase + (rem & 8), 20);
    } else {
        for (int j = beg; j < end; j += 4) {
            int4 s = *(const int4*)(srcadj + j);
            a0 = fmaf(RW(j + 0, k), cvt_lo(cmbI[s.x + lane]), a0);
            a1 = fmaf(RW(j + 1, k), cvt_lo(cmbI[s.y + lane]), a1);
            a2 = fmaf(RW(j + 2, k), cvt_lo(cmbI[s.z + lane]), a2);
            a3 = fmaf(RW(j + 3, k), cvt_lo(cmbI[s.w + lane]), a3);
        }
    }
    float acc = (a0 + a1) + (a2 + a3);

    if (flags & 1) {
        int i = node * DIM + lane;
        allemb[i] += acc;
        if (flags & 4) xnextU[i] = f2b(acc);
    }

    // routing score from register cache + fused per-slot S/weight update
    float ssu = red16(acc * acc);
    float u = acc / fmaxf(sqrtf(ssu), 1e-12f);
    bool b0 = lane & 1;
    bool b1 = lane & 2;
    bool b2 = lane & 4;
    bool b3 = lane & 8;

    if (!big) {
#define USC16(JOFF, TP0) do { \
        int j = beg + (JOFF); \
        float p0 = u * __uint_as_float(tp[(TP0) + 0] << 16); \
        float p1 = u * __uint_as_float(tp[(TP0) + 0] & 0xffff0000u); \
        float p2 = u * __uint_as_float(tp[(TP0) + 1] << 16); \
        float p3 = u * __uint_as_float(tp[(TP0) + 1] & 0xffff0000u); \
        float p4 = u * __uint_as_float(tp[(TP0) + 2] << 16); \
        float p5 = u * __uint_as_float(tp[(TP0) + 2] & 0xffff0000u); \
        float p6 = u * __uint_as_float(tp[(TP0) + 3] << 16); \
        float p7 = u * __uint_as_float(tp[(TP0) + 3] & 0xffff0000u); \
        float p8 = u * __uint_as_float(tp[(TP0) + 4] << 16); \
        float p9 = u * __uint_as_float(tp[(TP0) + 4] & 0xffff0000u); \
        float p10 = u * __uint_as_float(tp[(TP0) + 5] << 16); \
        float p11 = u * __uint_as_float(tp[(TP0) + 5] & 0xffff0000u); \
        float p12 = u * __uint_as_float(tp[(TP0) + 6] << 16); \
        float p13 = u * __uint_as_float(tp[(TP0) + 6] & 0xffff0000u); \
        float p14 = u * __uint_as_float(tp[(TP0) + 7] << 16); \
        float p15 = u * __uint_as_float(tp[(TP0) + 7] & 0xffff0000u); \
        float q0 = mixv(p0, p1, b0, 1); \
        float q1 = mixv(p2, p3, b0, 1); \
        float q2 = mixv(p4, p5, b0, 1); \
        float q3 = mixv(p6, p7, b0, 1); \
        float q4 = mixv(p8, p9, b0, 1); \
        float q5 = mixv(p10, p11, b0, 1); \
        float q6 = mixv(p12, p13, b0, 1); \
        float q7 = mixv(p14, p15, b0, 1); \
        float r0 = mixv(q0, q1, b1, 2); \
        float r1 = mixv(q2, q3, b1, 2); \
        float r2 = mixv(q4, q5, b1, 2); \
        float r3 = mixv(q6, q7, b1, 2); \
        float s0 = mixv(r0, r1, b2, 4); \
        float s1 = mixv(r2, r3, b2, 4); \
        float t0 = mixv(s0, s1, b3, 8); \
        fused_upd(j + (lane & 15), k, t0, true, \
                  rec4, S4f, wi, last, writeWi); \
} while (0)
        if (count >= 16) USC16(0, 0);
        if (count >= 32) USC16(16, 8);
        if (rem & 8) {
            int j = beg + rbase;
            float p0 = u * __uint_as_float(tp[16] << 16);
            float p1 = u * __uint_as_float(tp[16] & 0xffff0000u);
            float p2 = u * __uint_as_float(tp[17] << 16);
            float p3 = u * __uint_as_float(tp[17] & 0xffff0000u);
            float p4 = u * __uint_as_float(tp[18] << 16);
            float p5 = u * __uint_as_float(tp[18] & 0xffff0000u);
            float p6 = u * __uint_as_float(tp[19] << 16);
            float p7 = u * __uint_as_float(tp[19] & 0xffff0000u);
            float q0 = mixv(p0, p1, b0, 1);
            float q1 = mixv(p2, p3, b0, 1);
            float q2 = mixv(p4, p5, b0, 1);
            float q3 = mixv(p6, p7, b0, 1);
            float r0 = mixv(q0, q1, b1, 2);
            float r1 = mixv(q2, q3, b1, 2);
            float t0 = mixv(r0, r1, b2, 4);
            t0 += __shfl_xor(t0, 8);
            fused_upd(j + (lane & 7), k, t0, !(lane & 8),
                      rec4, S4f, wi, last, writeWi);
        }
        if (rem & 4) {
            int j = beg + rbase + (rem & 8);
            float p0 = u * __uint_as_float(tp[20] << 16);
            float p1 = u * __uint_as_float(tp[20] & 0xffff0000u);
            float p2 = u * __uint_as_float(tp[21] << 16);
            float p3 = u * __uint_as_float(tp[21] & 0xffff0000u);
            float q0 = mixv(p0, p1, b0, 1);
            float q1 = mixv(p2, p3, b0, 1);
            float r0 = mixv(q0, q1, b1, 2);
            r0 += __shfl_xor(r0, 4);
            r0 += __shfl_xor(r0, 8);
            fused_upd(j + (lane & 3), k, r0, !(lane & 12),
                      rec4, S4f, wi, last, writeWi);
        }
    } else {
        for (int j = beg; j < end; j += 4) {
            int4 s = *(const int4*)(srcadj + j);
            float p0 = red16(u * cvt_hi(cmbI[s.x + lane]));
            float p1 = red16(u * cvt_hi(cmbI[s.y + lane]));
            float p2 = red16(u * cvt_hi(cmbI[s.z + lane]));
            float p3 = red16(u * cvt_hi(cmbI[s.w + lane]));
            int sl = lane & 3;
            float dv = p0;
            dv = (sl == 1) ? p1 : dv;
            dv = (sl == 2) ? p2 : dv;
            dv = (sl == 3) ? p3 : dv;
            fused_upd(j + sl, k, dv, !(lane & 12),
                      rec4, S4f, wi, last, writeWi);
        }
    }
}

extern "C" void kernel_launch(void* const* d_in, const int* in_sizes, int n_in,
                              void* d_out, int out_size, void* d_ws, size_t ws_size,
                              hipStream_t stream) {
    const float* user = (const float*)d_in[0];
    const float* item = (const float*)d_in[1];
    const float* S_in = (const float*)d_in[2];
    const int* edge = (const int*)d_in[3];
    const int* row0 = edge;
    const int* col0 = edge + NE;

    float* out = (float*)d_out;
    float* allemb = out;              // NN*DIM floats
    float* Sfinal = out + NN * DIM;   // KF*NE floats

    char* ws = (char*)d_ws;
    size_t off = 0;
    auto carve = [&](size_t bytes) { void* p = ws + off; off += (bytes + 255) & ~(size_t)255; return p; };
    int* ptr = (int*)carve((NN + 1) * sizeof(int));
    int* bsum = (int*)carve(256 * sizeof(int));
    int* offs = (int*)carve(256 * sizeof(int));
    int* srcadj = (int*)carve((size_t)NSLOT_MAX * sizeof(int));
    int* rankR = (int*)carve((size_t)NE * sizeof(int));
    int* rankC = (int*)carve((size_t)NE * sizeof(int));
    int* jpos1 = (int*)carve((size_t)NE * sizeof(int));
    float* dinv = (float*)carve(NN * sizeof(float));
    float4* Scur4 = (float4*)carve((size_t)NEPU_MAX * sizeof(float4));
    // contiguous zero-region: cnt | rec (32B/user-slot) | wi  (ONE bulk memset)
    size_t zbeg = off;
    int* cnt = (int*)carve((NN + 1) * sizeof(int));
    int4* rec4 = (int4*)carve((size_t)NEPU_MAX * 2 * sizeof(int4));
    float4* wi = (float4*)carve((size_t)NEPI_MAX * sizeof(float4));
    size_t zlen = off - zbeg;
    unsigned short* egoUA = (unsigned short*)carve((size_t)NUM_USER * DIM * 2);
    unsigned short* egoUB = (unsigned short*)carve((size_t)NUM_USER * DIM * 2);
    unsigned* cmbIA = (unsigned*)carve((size_t)NUM_ITEM * DIM * 4);
    unsigned* cmbIB = (unsigned*)carve((size_t)NUM_ITEM * DIM * 4);

    hipMemsetAsync(ws + zbeg, 0, zlen, stream);

    k_setup<<<NB_SETUP, 256, 0, stream>>>(user, item, egoUA, cmbIA, allemb,
                                          row0, col0, cnt, rankR, rankC);
    k_scan1<<<NBLK_SCAN, SCAN_CHUNK, 0, stream>>>(cnt, dinv, ptr, bsum);
    k_scan2<<<1, 256, 0, stream>>>(bsum, offs);
    k_scan3<<<(NN + 1 + 255) / 256, 256, 0, stream>>>(ptr, offs, cnt, srcadj);
    k_fillw0<<<(NE + 255) / 256, 256, 0, stream>>>(row0, col0, rankR, rankC,
                                                   S_in, dinv, ptr, srcadj,
                                                   rec4, jpos1);

    unsigned short* egoU = egoUA;
    unsigned short* egoUn = egoUB;
    unsigned* cmbI = cmbIA;
    unsigned* cmbIn = cmbIB;
    for (int layer = 0; layer < 2; ++layer) {
        for (int it = 0; it < 2; ++it) {
            int flags = 0;
            if (it == 0) flags |= 8;                   // scatter wi (consumed at it=1)
            if (it == 1) flags |= 1;                   // layer end: allemb += acc
            if (it == 1 && layer == 0) flags |= 4;     // write next ego (+item T)
            int last = (layer == 1 && it == 1) ? 1 : 0;
            // non-layer-end: item x_new is never consumed -> user-only grid
            int nlim = (it == 1) ? NN : NUM_USER;
            k_conv_score<<<(nlim * 64 + 255) / 256, 256, 0, stream>>>(
                ptr, srcadj, rec4, (float*)wi, (float*)Scur4,
                egoU, cmbI, egoUn, cmbIn, allemb, flags, last, nlim);
        }
        unsigned short* t = egoU; egoU = egoUn; egoUn = t;
        unsigned* tc = cmbI; cmbI = cmbIn; cmbIn = tc;
    }
    k_sout<<<(NE + 255) / 256, 256, 0, stream>>>(Scur4, jpos1, Sfinal);
}